// Round 9
// baseline (848.513 us; speedup 1.0000x reference)
//
#include <hip/hip_runtime.h>
#include <cmath>

#define NM 1043
#define ND 2166
#define KS 2  // attention key-splits

static inline int ceil_div(int a, int b) { return (a + b - 1) / b; }

typedef __attribute__((ext_vector_type(8))) short bf16x8;
typedef __attribute__((ext_vector_type(4))) float f32x4;
typedef __attribute__((ext_vector_type(2))) unsigned int u32x2;
typedef __attribute__((ext_vector_type(4))) unsigned int u32x4;

union U8 { u32x4 u; bf16x8 h; };

__device__ inline unsigned int pkbf(float a, float b) {
  unsigned int ua = __float_as_uint(a), ub = __float_as_uint(b);
  ua += 0x7FFFu + ((ua >> 16) & 1);
  ub += 0x7FFFu + ((ub >> 16) & 1);
  return (ub & 0xFFFF0000u) | (ua >> 16);
}

__device__ inline unsigned short bf1(float a) {
  unsigned int ua = __float_as_uint(a);
  ua += 0x7FFFu + ((ua >> 16) & 1);
  return (unsigned short)(ua >> 16);
}

// ============ weight prep: W[k][n] f32 -> Wt[n][k] bf16 (16 matrices) ========
struct PrepW { const float* W[16]; unsigned short* Wt[16]; };

__global__ __launch_bounds__(256) void prep_w(PrepW p) {
  const int z = blockIdx.z;
  const float* __restrict__ W = p.W[z];
  unsigned short* __restrict__ Wt = p.Wt[z];
  const int n0 = blockIdx.x * 64, k0 = blockIdx.y * 64;
  __shared__ float Ws[64][65];
  const int tid = threadIdx.x;
#pragma unroll
  for (int it = 0; it < 16; it++) {
    int i = it * 256 + tid;
    int k = i >> 6, n = i & 63;
    Ws[k][n] = W[(size_t)(k0 + k) * 512 + n0 + n];
  }
  __syncthreads();
#pragma unroll
  for (int it = 0; it < 16; it++) {
    int i = it * 256 + tid;
    int n = i >> 6, k = i & 63;
    Wt[(size_t)(n0 + n) * 512 + k0 + k] = bf1(Ws[k][n]);
  }
}

// ============ batched MFMA GEMM: C[M,512] = A[M,512] @ W, Bt = W^T bf16 ======
struct BGemm {
  const void* A[6]; const unsigned short* Bt[6]; void* C[6];
  int M[6]; int lda[6];
};

template<int AIN_BF16, int COUT_BF16>
__global__ __launch_bounds__(256) void gemm_mfma(BGemm g) {
  const int z = blockIdx.z;
  const int M = g.M[z];
  const int bm = blockIdx.y << 7;
  if (bm >= M) return;
  const int bn = blockIdx.x << 7;
  const int lda = g.lda[z];
  const char* __restrict__ Ab = (const char*)g.A[z];
  const char* __restrict__ Btb = (const char*)g.Bt[z];

  __shared__ short As_s[128 * 64];
  __shared__ short Bs_s[128 * 64];
  char* asb = (char*)As_s;
  char* bsb = (char*)Bs_s;

  const int tid = threadIdx.x;
  const int lane = tid & 63;
  const int w = tid >> 6;
  const int wm = (w >> 1) << 6, wn = (w & 1) << 6;
  const int fr = lane & 15, kg = lane >> 4;

  f32x4 acc[4][4];
#pragma unroll
  for (int i = 0; i < 4; i++)
#pragma unroll
    for (int j = 0; j < 4; j++) acc[i][j] = (f32x4){0.f, 0.f, 0.f, 0.f};

  for (int kb = 0; kb < 512; kb += 64) {
    __syncthreads();
#pragma unroll
    for (int qi = 0; qi < 4; qi++) {
      int qid = qi * 256 + tid;
      int mm = qid >> 3, qk = qid & 7;
      u32x4 wv = {0u, 0u, 0u, 0u};
      if (bm + mm < M) {
        if (AIN_BF16) {
          wv = *(const u32x4*)(Ab + ((size_t)(bm + mm) * lda + kb + qk * 8) * 2);
        } else {
          const float* ap = (const float*)Ab + (size_t)(bm + mm) * lda + kb + qk * 8;
          float4 f0 = ((const float4*)ap)[0];
          float4 f1 = ((const float4*)ap)[1];
          wv.x = pkbf(f0.x, f0.y); wv.y = pkbf(f0.z, f0.w);
          wv.z = pkbf(f1.x, f1.y); wv.w = pkbf(f1.z, f1.w);
        }
      }
      *(u32x4*)(asb + mm * 128 + ((qk * 16) ^ ((mm & 7) << 4))) = wv;
    }
#pragma unroll
    for (int qi = 0; qi < 4; qi++) {
      int qid = qi * 256 + tid;
      int nn = qid >> 3, qk = qid & 7;
      u32x4 bv = *(const u32x4*)(Btb + (((size_t)(bn + nn)) << 10) + (kb + qk * 8) * 2);
      *(u32x4*)(bsb + nn * 128 + ((qk * 16) ^ ((nn & 7) << 4))) = bv;
    }
    __syncthreads();

#pragma unroll
    for (int ks = 0; ks < 2; ks++) {
      bf16x8 af[4], bfv[4];
#pragma unroll
      for (int i = 0; i < 4; i++) {
        int row = wm + i * 16 + fr;
        af[i] = *(const bf16x8*)(asb + row * 128 + (((ks * 64) + kg * 16) ^ ((row & 7) << 4)));
      }
#pragma unroll
      for (int j = 0; j < 4; j++) {
        int row = wn + j * 16 + fr;
        bfv[j] = *(const bf16x8*)(bsb + row * 128 + (((ks * 64) + kg * 16) ^ ((row & 7) << 4)));
      }
#pragma unroll
      for (int i = 0; i < 4; i++)
#pragma unroll
        for (int j = 0; j < 4; j++)
          acc[i][j] = __builtin_amdgcn_mfma_f32_16x16x32_bf16(af[i], bfv[j], acc[i][j], 0, 0, 0);
    }
  }

#pragma unroll
  for (int i = 0; i < 4; i++) {
    int m0 = bm + wm + i * 16 + kg * 4;
#pragma unroll
    for (int j = 0; j < 4; j++) {
      int n = bn + wn + j * 16 + fr;
#pragma unroll
      for (int r = 0; r < 4; r++) {
        if (m0 + r < M) {
          if (COUT_BF16) ((unsigned short*)g.C[z])[(size_t)(m0 + r) * 512 + n] = bf1(acc[i][j][r]);
          else ((float*)g.C[z])[(size_t)(m0 + r) * 512 + n] = acc[i][j][r];
        }
      }
    }
  }
}

// ================= final TN GEMM (f32, unchanged) =================
__global__ __launch_bounds__(256) void gemm_tn(
    const float* __restrict__ A, const float* __restrict__ B, float* __restrict__ C,
    int M, int N, int K, int lda, int ldb, int ldc) {
  __shared__ float As[16][65];
  __shared__ float Bs[16][65];
  const int tid = threadIdx.x;
  const int tx = tid & 15, ty = tid >> 4;
  const int bm = blockIdx.y << 6, bn = blockIdx.x << 6;
  float acc[4][4] = {};
  for (int k0 = 0; k0 < K; k0 += 16) {
    for (int i = tid; i < 16 * 64; i += 256) {
      int kk = i >> 6, mm = i & 63;
      int r = k0 + kk, c = bm + mm;
      As[kk][mm] = (r < K && c < M) ? A[(size_t)r * lda + c] : 0.f;
    }
    for (int i = tid; i < 16 * 64; i += 256) {
      int kk = i >> 6, nn = i & 63;
      int r = k0 + kk, c = bn + nn;
      Bs[kk][nn] = (r < K && c < N) ? B[(size_t)r * ldb + c] : 0.f;
    }
    __syncthreads();
#pragma unroll
    for (int kk = 0; kk < 16; kk++) {
      float a[4], b[4];
#pragma unroll
      for (int i = 0; i < 4; i++) a[i] = As[kk][ty + (i << 4)];
#pragma unroll
      for (int j = 0; j < 4; j++) b[j] = Bs[kk][tx + (j << 4)];
#pragma unroll
      for (int i = 0; i < 4; i++)
#pragma unroll
        for (int j = 0; j < 4; j++) acc[i][j] += a[i] * b[j];
    }
    __syncthreads();
  }
#pragma unroll
  for (int i = 0; i < 4; i++) {
    int r = bm + ty + (i << 4);
    if (r >= M) continue;
#pragma unroll
    for (int j = 0; j < 4; j++) {
      int c = bn + tx + (j << 4);
      if (c < N) C[(size_t)r * ldc + c] = acc[i][j];
    }
  }
}

// ================= GCN: CSR build + fused gather =================
struct DegB {
  const int* dst[4]; const float* attr[4];
  float* dis[4]; int* cnt[4];
  int epref[5];
};

__global__ __launch_bounds__(256) void deg_count_b(DegB g) {
  int et = blockIdx.x * 256 + threadIdx.x;
  if (et >= g.epref[4]) return;
  int z = (et >= g.epref[1]) + (et >= g.epref[2]) + (et >= g.epref[3]);
  int e = et - g.epref[z];
  int d = g.dst[z][e];
  atomicAdd(&g.dis[z][d], g.attr[z][e]);
  atomicAdd(&g.cnt[z][d], 1);
}

struct FinB { float* dis[4]; int n[4]; };

__global__ __launch_bounds__(256) void finish_dis_b(FinB g) {
  int z = blockIdx.z;
  int i = blockIdx.x * 256 + threadIdx.x;
  if (i < g.n[z]) g.dis[z][i] = rsqrtf(g.dis[z][i] + 1.0f);
}

struct ScanB { const int* cnt[4]; int* rowptr[4]; int n[4]; };

__global__ __launch_bounds__(256) void scan_b(ScanB s) {
  int z = blockIdx.x;
  int n = s.n[z];
  const int* cnt = s.cnt[z];
  int* rp = s.rowptr[z];
  __shared__ int sums[256];
  int tid = threadIdx.x;
  int chunk = (n + 255) >> 8;
  int start = tid * chunk;
  int local = 0;
  for (int i = 0; i < chunk; i++) {
    int idx = start + i;
    if (idx < n) local += cnt[idx];
  }
  sums[tid] = local;
  __syncthreads();
  for (int off = 1; off < 256; off <<= 1) {
    int t = (tid >= off) ? sums[tid - off] : 0;
    __syncthreads();
    sums[tid] += t;
    __syncthreads();
  }
  int base = sums[tid] - local;
  int total = sums[255];
  int run = base;
  for (int i = 0; i < chunk; i++) {
    int idx = start + i;
    if (idx < n) { rp[idx] = run; run += cnt[idx]; }
  }
  if (tid == 0) rp[n] = total;
}

struct FillB {
  const int* src[4]; const int* dst[4]; const float* attr[4];
  const int* rowptr[4]; int* cur[4]; int* col[4]; float* val[4];
  int epref[5];
};

__global__ __launch_bounds__(256) void fill_b(FillB f) {
  int et = blockIdx.x * 256 + threadIdx.x;
  if (et >= f.epref[4]) return;
  int z = (et >= f.epref[1]) + (et >= f.epref[2]) + (et >= f.epref[3]);
  int e = et - f.epref[z];
  int d = f.dst[z][e];
  int pos = f.rowptr[z][d] + atomicAdd(&f.cur[z][d], 1);
  f.col[z][pos] = f.src[z][e];
  f.val[z][pos] = f.attr[z][e];
}

struct GathB {
  const int* rowptr[4]; const int* col[4]; const float* val[4];
  const float* dis[4]; const float* h[4]; const float* b[4];
  float* out[4]; int n[4];
};

__global__ __launch_bounds__(256) void gcn_gather_b(GathB c) {
  const int z = blockIdx.z;
  const int node = blockIdx.x;
  if (node >= c.n[z]) return;
  const int tid = threadIdx.x;
  const int* __restrict__ col = c.col[z];
  const float* __restrict__ val = c.val[z];
  const float* __restrict__ dis = c.dis[z];
  const float* __restrict__ h = c.h[z];
  const int beg = c.rowptr[z][node], end = c.rowptr[z][node + 1];
  float acc0 = 0.f, acc1 = 0.f;
  int e = beg;
  for (; e + 4 <= end; e += 4) {
    int s0 = col[e], s1 = col[e + 1], s2 = col[e + 2], s3 = col[e + 3];
    float w0 = val[e] * dis[s0];
    float w1 = val[e + 1] * dis[s1];
    float w2 = val[e + 2] * dis[s2];
    float w3 = val[e + 3] * dis[s3];
    const float* p0 = h + ((size_t)s0 << 9);
    const float* p1 = h + ((size_t)s1 << 9);
    const float* p2 = h + ((size_t)s2 << 9);
    const float* p3 = h + ((size_t)s3 << 9);
    acc0 += w0 * p0[tid] + w1 * p1[tid] + w2 * p2[tid] + w3 * p3[tid];
    acc1 += w0 * p0[tid + 256] + w1 * p1[tid + 256] + w2 * p2[tid + 256] + w3 * p3[tid + 256];
  }
  for (; e < end; e++) {
    int s = col[e];
    float w = val[e] * dis[s];
    const float* p = h + ((size_t)s << 9);
    acc0 += w * p[tid];
    acc1 += w * p[tid + 256];
  }
  const float dd = dis[node];
  const float* hp = h + ((size_t)node << 9);
  float o0 = fmaxf(dd * acc0 + dd * dd * hp[tid] + c.b[z][tid], 0.f);
  float o1 = fmaxf(dd * acc1 + dd * dd * hp[tid + 256] + c.b[z][tid + 256], 0.f);
  float* op = c.out[z] + (size_t)node * 2048;
  op[tid] = o0;
  op[tid + 256] = o1;
}

// ================= view gather =================
struct GatherB { const float* emb[2]; float* xv[2]; int n[2]; };

__global__ __launch_bounds__(256) void gather_b(GatherB g) {
  int z = blockIdx.z;
  int n = g.n[z];
  size_t i = (size_t)blockIdx.x * 256 + threadIdx.x;
  if (i >= (size_t)n * 2048) return;
  int e = (int)(i & 511);
  size_t t = i >> 9;
  int v = (int)(t / n);
  int nn = (int)(t - (size_t)v * n);
  g.xv[z][i] = g.emb[z][((size_t)v * 512 + e) * n + nn];
}

// ================= attention v5: split-K flash, bf16 in, f32 partials ========
// Each block: 128 q-rows x one key-split. Writes unnormalized O~ (f32) + (m,l).
// Softmax in base-2: S_scaled = S * 0.125 * log2(e); p = exp2(S_scaled - m).
#define ATT_SC 0.18033688011112042f  // 0.125 * log2(e)

struct AttArgs {
  const unsigned short* Q[2]; const unsigned short* K[2]; const unsigned short* V[2];
  float* Op[2];   // [KS][4N*512] f32 partials
  float* ml[2];   // [KS][4N*16]  (m,l) per (v*N+q, h)
  int N[2];
};

__global__ __launch_bounds__(256) void attn5_kernel(AttArgs ar) {
  const int z = blockIdx.z;
  const int N = ar.N[z];
  const int qi = blockIdx.x / KS, ks = blockIdx.x % KS;
  const int qb = qi * 128;
  if (qb >= N) return;
  const int vh = blockIdx.y, v = vh >> 3, h = vh & 7;
  const size_t base = (size_t)v * N * 512 + (size_t)h * 64;
  const unsigned short* __restrict__ Qb = ar.Q[z] + base;
  const char* __restrict__ Kc = (const char*)(ar.K[z] + base);
  const char* __restrict__ Vc = (const char*)(ar.V[z] + base);
  const size_t sstride = (size_t)4 * N * 512;
  float* __restrict__ Opb = ar.Op[z] + (size_t)ks * sstride + base;
  float* __restrict__ mlb = ar.ml[z] + (size_t)ks * 4 * N * 16;

  __shared__ short kt_s[64 * 64];
  __shared__ short vt_s[64 * 64];
  char* ktb = (char*)kt_s;
  char* vtb = (char*)vt_s;

  const int tid = threadIdx.x;
  const int lane = tid & 63;
  const int w = tid >> 6;
  const int a15 = lane & 15;
  const int g = lane >> 4;

  const int qA = qb + w * 32 + a15;
  const int qB = qA + 16;
  bf16x8 qfA0 = {}, qfA1 = {}, qfB0 = {}, qfB1 = {};
  if (qA < N) {
    qfA0 = *(const bf16x8*)(Qb + (size_t)qA * 512 + g * 8);
    qfA1 = *(const bf16x8*)(Qb + (size_t)qA * 512 + 32 + g * 8);
  }
  if (qB < N) {
    qfB0 = *(const bf16x8*)(Qb + (size_t)qB * 512 + g * 8);
    qfB1 = *(const bf16x8*)(Qb + (size_t)qB * 512 + 32 + g * 8);
  }

  float rmA = -INFINITY, rsA = 0.f, rmB = -INFINITY, rsB = 0.f;
  f32x4 oA0 = {0.f, 0.f, 0.f, 0.f}, oA1 = oA0, oA2 = oA0, oA3 = oA0;
  f32x4 oB0 = oA0, oB1 = oA0, oB2 = oA0, oB3 = oA0;

  const int swzk = (a15 & 7) << 4;
  const int swzv = a15 << 3;
  const int skr = tid >> 2, skq = (tid & 3) * 16;
  const int vsr = tid & 15, vsc = tid >> 4;

  const int nt = (N + 63) >> 6;
  const int nth = nt >> 1;
  const int t0 = ks ? nth : 0;
  const int t1 = ks ? nt : nth;

  for (int t = t0; t < t1; t++) {
    const int kb = t << 6;
    __syncthreads();
    // ---- stage K (bf16 copy, swizzled) ----
    {
      const int sw = (skr & 7) << 4;
      const char* kp = Kc + (size_t)(kb + skr) * 1024;
      u32x4 k0 = {0u,0u,0u,0u}, k1 = {0u,0u,0u,0u};
      if (kb + skr < N) {
        k0 = *(const u32x4*)(kp + skq);
        k1 = *(const u32x4*)(kp + skq + 64);
      }
      *(u32x4*)(ktb + skr * 128 + (skq ^ sw)) = k0;
      *(u32x4*)(ktb + skr * 128 + ((skq + 64) ^ sw)) = k1;
    }
    // ---- stage V transposed (register bf16 transpose, swizzled) ----
    {
      const int r0 = kb + 4 * vsr;
      u32x2 i0 = {0u,0u}, i1 = {0u,0u}, i2 = {0u,0u}, i3 = {0u,0u};
      const char* vp = Vc + (size_t)r0 * 1024 + vsc * 8;
      if (r0 + 0 < N) i0 = *(const u32x2*)(vp);
      if (r0 + 1 < N) i1 = *(const u32x2*)(vp + 1024);
      if (r0 + 2 < N) i2 = *(const u32x2*)(vp + 2048);
      if (r0 + 3 < N) i3 = *(const u32x2*)(vp + 3072);
      const int dd = 4 * vsc, kby = 8 * vsr;
      u32x2 o;
      o.x = (i0.x & 0xFFFFu) | (i1.x << 16); o.y = (i2.x & 0xFFFFu) | (i3.x << 16);
      *(u32x2*)(vtb + (dd + 0) * 128 + (kby ^ (((dd + 0) & 15) << 3))) = o;
      o.x = (i0.x >> 16) | (i1.x & 0xFFFF0000u); o.y = (i2.x >> 16) | (i3.x & 0xFFFF0000u);
      *(u32x2*)(vtb + (dd + 1) * 128 + (kby ^ (((dd + 1) & 15) << 3))) = o;
      o.x = (i0.y & 0xFFFFu) | (i1.y << 16); o.y = (i2.y & 0xFFFFu) | (i3.y << 16);
      *(u32x2*)(vtb + (dd + 2) * 128 + (kby ^ (((dd + 2) & 15) << 3))) = o;
      o.x = (i0.y >> 16) | (i1.y & 0xFFFF0000u); o.y = (i2.y >> 16) | (i3.y & 0xFFFF0000u);
      *(u32x2*)(vtb + (dd + 3) * 128 + (kby ^ (((dd + 3) & 15) << 3))) = o;
    }
    __syncthreads();

    // ---- QK^T (K fragments shared between q-tiles) ----
    f32x4 sA0 = {0.f,0.f,0.f,0.f}, sA1 = sA0, sA2 = sA0, sA3 = sA0;
    f32x4 sB0 = sA0, sB1 = sA0, sB2 = sA0, sB3 = sA0;
#define QK2(m, sAm, sBm, s2, qfa, qfb) { \
    bf16x8 kf = *(const bf16x8*)(ktb + (16 * m + a15) * 128 + ((64 * s2 + 16 * g) ^ swzk)); \
    sAm = __builtin_amdgcn_mfma_f32_16x16x32_bf16(kf, qfa, sAm, 0, 0, 0); \
    sBm = __builtin_amdgcn_mfma_f32_16x16x32_bf16(kf, qfb, sBm, 0, 0, 0); }
    QK2(0, sA0, sB0, 0, qfA0, qfB0) QK2(1, sA1, sB1, 0, qfA0, qfB0)
    QK2(2, sA2, sB2, 0, qfA0, qfB0) QK2(3, sA3, sB3, 0, qfA0, qfB0)
    QK2(0, sA0, sB0, 1, qfA1, qfB1) QK2(1, sA1, sB1, 1, qfA1, qfB1)
    QK2(2, sA2, sB2, 1, qfA1, qfB1) QK2(3, sA3, sB3, 1, qfA1, qfB1)
#undef QK2

    // scale into base-2 domain
    sA0 *= ATT_SC; sA1 *= ATT_SC; sA2 *= ATT_SC; sA3 *= ATT_SC;
    sB0 *= ATT_SC; sB1 *= ATT_SC; sB2 *= ATT_SC; sB3 *= ATT_SC;

    if (kb + 64 > N) {
#define MSK(sfm, sgm, m) { int kk = kb + 16 * m + 4 * g; \
      if (kk + 0 >= N) { sfm.x = -INFINITY; sgm.x = -INFINITY; } \
      if (kk + 1 >= N) { sfm.y = -INFINITY; sgm.y = -INFINITY; } \
      if (kk + 2 >= N) { sfm.z = -INFINITY; sgm.z = -INFINITY; } \
      if (kk + 3 >= N) { sfm.w = -INFINITY; sgm.w = -INFINITY; } }
      MSK(sA0, sB0, 0) MSK(sA1, sB1, 1) MSK(sA2, sB2, 2) MSK(sA3, sB3, 3)
#undef MSK
    }

#define SMX(sfm, prm) { float e; unsigned int u; \
    e = exp2f(sfm.x - nm); u = __float_as_uint(e); u += 0x7FFFu + ((u >> 16) & 1); u &= 0xFFFF0000u; ps += __uint_as_float(u); prm.x = u; \
    e = exp2f(sfm.y - nm); u = __float_as_uint(e); u += 0x7FFFu + ((u >> 16) & 1); u &= 0xFFFF0000u; ps += __uint_as_float(u); prm.y = u; \
    e = exp2f(sfm.z - nm); u = __float_as_uint(e); u += 0x7FFFu + ((u >> 16) & 1); u &= 0xFFFF0000u; ps += __uint_as_float(u); prm.z = u; \
    e = exp2f(sfm.w - nm); u = __float_as_uint(e); u += 0x7FFFu + ((u >> 16) & 1); u &= 0xFFFF0000u; ps += __uint_as_float(u); prm.w = u; }
#define PV(md, om, s2, pbr) { \
    const char* vr = vtb + (16 * md + a15) * 128; \
    u32x2 v0 = *(const u32x2*)(vr + ((64 * s2 + 8 * g) ^ swzv)); \
    u32x2 v1 = *(const u32x2*)(vr + ((64 * s2 + 32 + 8 * g) ^ swzv)); \
    U8 av; av.u.x = v0.x; av.u.y = v0.y; av.u.z = v1.x; av.u.w = v1.y; \
    om = __builtin_amdgcn_mfma_f32_16x16x32_bf16(av.h, pbr, om, 0, 0, 0); }
#define SOFTMAX_PV(sf0, sf1, sf2, sf3, rm, rs, q0, q1, q2, q3) { \
    float tmax = fmaxf(fmaxf(fmaxf(sf0.x, sf0.y), fmaxf(sf0.z, sf0.w)), \
                       fmaxf(fmaxf(sf1.x, sf1.y), fmaxf(sf1.z, sf1.w))); \
    tmax = fmaxf(tmax, fmaxf(fmaxf(fmaxf(sf2.x, sf2.y), fmaxf(sf2.z, sf2.w)), \
                             fmaxf(fmaxf(sf3.x, sf3.y), fmaxf(sf3.z, sf3.w)))); \
    tmax = fmaxf(tmax, __shfl_xor(tmax, 16)); \
    tmax = fmaxf(tmax, __shfl_xor(tmax, 32)); \
    const float nm = fmaxf(rm, tmax); \
    const float sc = exp2f(rm - nm); \
    float ps = 0.f; \
    u32x4 pr0, pr1, pr2, pr3; \
    SMX(sf0, pr0) SMX(sf1, pr1) SMX(sf2, pr2) SMX(sf3, pr3) \
    ps += __shfl_xor(ps, 16); \
    ps += __shfl_xor(ps, 32); \
    rs = rs * sc + ps; \
    rm = nm; \
    q0 *= sc; q1 *= sc; q2 *= sc; q3 *= sc; \
    U8 pb0, pb1; \
    pb0.u.x = (pr0.x >> 16) | pr0.y;  pb0.u.y = (pr0.z >> 16) | pr0.w; \
    pb0.u.z = (pr1.x >> 16) | pr1.y;  pb0.u.w = (pr1.z >> 16) | pr1.w; \
    pb1.u.x = (pr2.x >> 16) | pr2.y;  pb1.u.y = (pr2.z >> 16) | pr2.w; \
    pb1.u.z = (pr3.x >> 16) | pr3.y;  pb1.u.w = (pr3.z >> 16) | pr3.w; \
    PV(0, q0, 0, pb0.h) PV(1, q1, 0, pb0.h) PV(2, q2, 0, pb0.h) PV(3, q3, 0, pb0.h) \
    PV(0, q0, 1, pb1.h) PV(1, q1, 1, pb1.h) PV(2, q2, 1, pb1.h) PV(3, q3, 1, pb1.h) }

    SOFTMAX_PV(sA0, sA1, sA2, sA3, rmA, rsA, oA0, oA1, oA2, oA3)
    SOFTMAX_PV(sB0, sB1, sB2, sB3, rmB, rsB, oB0, oB1, oB2, oB3)
#undef SOFTMAX_PV
#undef PV
#undef SMX
  }

  // ---- store unnormalized partial O (f32) + (m,l) ----
  if (qA < N) {
    float* op = Opb + (size_t)qA * 512 + 4 * g;
    *(f32x4*)(op + 0)  = oA0;
    *(f32x4*)(op + 16) = oA1;
    *(f32x4*)(op + 32) = oA2;
    *(f32x4*)(op + 48) = oA3;
    if (g == 0) {
      float* mp = mlb + ((size_t)v * N + qA) * 16 + h * 2;
      mp[0] = rmA; mp[1] = rsA;
    }
  }
  if (qB < N) {
    float* op = Opb + (size_t)qB * 512 + 4 * g;
    *(f32x4*)(op + 0)  = oB0;
    *(f32x4*)(op + 16) = oB1;
    *(f32x4*)(op + 32) = oB2;
    *(f32x4*)(op + 48) = oB3;
    if (g == 0) {
      float* mp = mlb + ((size_t)v * N + qB) * 16 + h * 2;
      mp[0] = rmB; mp[1] = rsB;
    }
  }
}

// ---- merge: O = sum_ks O~_ks * 2^(m_ks - m*) / sum_ks l_ks * 2^(m_ks - m*) --
struct MergeB {
  const float* Op[2]; const float* ml[2];
  unsigned short* O[2]; int N[2];
};

__global__ __launch_bounds__(256) void attn_merge_b(MergeB mg) {
  const int z = blockIdx.z;
  const int N = mg.N[z];
  const size_t tot = (size_t)4 * N * 128;  // 4 elems per thread
  size_t idx = (size_t)blockIdx.x * 256 + threadIdx.x;
  if (idx >= tot) return;
  const size_t i = idx * 4;
  const size_t nq = i >> 9;          // v*N + q
  const int e = (int)(i & 511);
  const int h = e >> 6;
  const size_t sstride = (size_t)4 * N * 512;
  const float* mlp0 = mg.ml[z] + nq * 16 + h * 2;
  const float* mlp1 = mg.ml[z] + (size_t)4 * N * 16 + nq * 16 + h * 2;
  const float m0 = mlp0[0], l0 = mlp0[1];
  const float m1 = mlp1[0], l1 = mlp1[1];
  const float mm = fmaxf(m0, m1);
  const float w0 = exp2f(m0 - mm), w1 = exp2f(m1 - mm);
  const float inv = 1.0f / (l0 * w0 + l1 * w1);
  const float4 a = *(const float4*)(mg.Op[z] + i);
  const float4 b = *(const float4*)(mg.Op[z] + sstride + i);
  const float s0 = w0 * inv, s1 = w1 * inv;
  u32x2 r;
  r.x = pkbf(a.x * s0 + b.x * s1, a.y * s0 + b.y * s1);
  r.y = pkbf(a.z * s0 + b.z * s1, a.w * s0 + b.w * s1);
  *(u32x2*)(mg.O[z] + i) = r;
}

// ================= fuse =================
struct FuseB { const float* mha[2]; const float* fw[2]; const float* fb[2]; float* y[2]; int n[2]; };

__global__ __launch_bounds__(256) void fuse_b(FuseB fz) {
  int z = blockIdx.z;
  int n = fz.n[z];
  int i = blockIdx.x * 256 + threadIdx.x;
  if (i >= n * 512) return;
  size_t stride = (size_t)n * 512;
  const float* m = fz.mha[z];
  const float* fw = fz.fw[z];
  float acc = fz.fb[z][0];
  acc += fw[0] * m[i];
  acc += fw[1] * m[stride + i];
  acc += fw[2] * m[2 * stride + i];
  acc += fw[3] * m[3 * stride + i];
  fz.y[z][i] = acc;
}

// ================= launch =================
extern "C" void kernel_launch(void* const* d_in, const int* in_sizes, int n_in,
                              void* d_out, int out_size, void* d_ws, size_t ws_size,
                              hipStream_t stream) {
  const float* mirna_x = (const float*)d_in[0];
  const float* drug_x  = (const float*)d_in[1];
  const int* edge[4] = { (const int*)d_in[2], (const int*)d_in[4], (const int*)d_in[6], (const int*)d_in[8] };
  const float* attr[4] = { (const float*)d_in[3], (const float*)d_in[5], (const float*)d_in[7], (const float*)d_in[9] };
  const int m[4] = { in_sizes[2] / 2, in_sizes[4] / 2, in_sizes[6] / 2, in_sizes[8] / 2 };
  const int nn4[4] = { NM, NM, ND, ND };
  float* out = (float*)d_out;

  float* ws = (float*)d_ws;
  size_t off = 0;
  auto take = [&](size_t nelem) {
    float* r = ws + off;
    off += (nelem + 255) & ~(size_t)255;
    return r;
  };
  const size_t HN = (size_t)NM * 512, HD = (size_t)ND * 512;
  const size_t HALL = 2 * HN + 2 * HD;
  float* emb_m = take((size_t)NM * 2048);
  float* emb_d = take((size_t)ND * 2048);
  float* region = take(2 * HALL);
  float* h4[4] = { region, region + HN, region + 2 * HN, region + 2 * HN + HD };
  float* xv_m = region;
  float* xv_d = region + (size_t)NM * 2048;
  float* dis_all = take(4 * 2560);
  float* dis4[4] = { dis_all, dis_all + 2560, dis_all + 2 * 2560, dis_all + 3 * 2560 };
  int* cnt_all = (int*)take(4 * 2560);
  int* cnt4[4] = { cnt_all, cnt_all + 2560, cnt_all + 2 * 2560, cnt_all + 3 * 2560 };
  int* rp_all = (int*)take(4 * 2304);
  int* rp4[4] = { rp_all, rp_all + 2304, rp_all + 2 * 2304, rp_all + 3 * 2304 };
  int* col4[4];
  float* val4[4];
  for (int z = 0; z < 4; z++) {
    col4[z] = (int*)take(m[z]);
    val4[z] = take(m[z]);
  }
  unsigned short* Qm = (unsigned short*)take((size_t)NM * 1024);
  unsigned short* Km = (unsigned short*)take((size_t)NM * 1024);
  unsigned short* Vm = (unsigned short*)take((size_t)NM * 1024);
  unsigned short* Qd = (unsigned short*)take((size_t)ND * 1024);
  unsigned short* Kd = (unsigned short*)take((size_t)ND * 1024);
  unsigned short* Vd = (unsigned short*)take((size_t)ND * 1024);
  float* mha_m = take((size_t)NM * 2048);
  float* mha_d = take((size_t)ND * 2048);
  float* y_m = take(HN);
  float* y_d = take(HD);
  unsigned short* wt = (unsigned short*)take((size_t)16 * 131072);
  float* Op_m = take((size_t)KS * NM * 2048);
  float* Op_d = take((size_t)KS * ND * 2048);
  float* ml_m = take((size_t)KS * NM * 4 * 16);
  float* ml_d = take((size_t)KS * ND * 4 * 16);

  int pref = 0;
  int epref[5];
  for (int z = 0; z < 4; z++) { epref[z] = pref; pref += m[z]; }
  epref[4] = pref;

  // -------- weight prep --------
  PrepW pw;
  for (int z = 0; z < 4; z++) {
    pw.W[z] = (const float*)d_in[10 + 4 * z];
    pw.W[4 + z] = (const float*)d_in[12 + 4 * z];
    pw.W[8 + z] = (const float*)d_in[26 + z];
    pw.W[12 + z] = (const float*)d_in[32 + z];
  }
  for (int z = 0; z < 16; z++) pw.Wt[z] = wt + (size_t)z * 262144;
  prep_w<<<dim3(8, 8, 16), 256, 0, stream>>>(pw);

  // -------- CSR build --------
  hipMemsetAsync(dis_all, 0, 4 * 2560 * sizeof(float), stream);
  hipMemsetAsync(cnt_all, 0, 4 * 2560 * sizeof(int), stream);

  DegB db;
  for (int z = 0; z < 4; z++) {
    db.dst[z] = edge[z] + m[z]; db.attr[z] = attr[z];
    db.dis[z] = dis4[z]; db.cnt[z] = cnt4[z];
  }
  for (int z = 0; z < 5; z++) db.epref[z] = epref[z];
  deg_count_b<<<ceil_div(pref, 256), 256, 0, stream>>>(db);

  FinB fn;
  for (int z = 0; z < 4; z++) { fn.dis[z] = dis4[z]; fn.n[z] = nn4[z]; }
  finish_dis_b<<<dim3(ceil_div(ND, 256), 1, 4), 256, 0, stream>>>(fn);

  ScanB sb;
  for (int z = 0; z < 4; z++) { sb.cnt[z] = cnt4[z]; sb.rowptr[z] = rp4[z]; sb.n[z] = nn4[z]; }
  scan_b<<<4, 256, 0, stream>>>(sb);

  hipMemsetAsync(cnt_all, 0, 4 * 2560 * sizeof(int), stream);
  FillB fl;
  for (int z = 0; z < 4; z++) {
    fl.src[z] = edge[z]; fl.dst[z] = edge[z] + m[z]; fl.attr[z] = attr[z];
    fl.rowptr[z] = rp4[z]; fl.cur[z] = cnt4[z]; fl.col[z] = col4[z]; fl.val[z] = val4[z];
  }
  for (int z = 0; z < 5; z++) fl.epref[z] = epref[z];
  fill_b<<<ceil_div(pref, 256), 256, 0, stream>>>(fl);

  // -------- conv1 --------
  BGemm c1;
  const float* xin[4] = { mirna_x, mirna_x, drug_x, drug_x };
  for (int z = 0; z < 4; z++) {
    c1.A[z] = xin[z]; c1.Bt[z] = wt + (size_t)z * 262144; c1.C[z] = h4[z];
    c1.M[z] = nn4[z]; c1.lda[z] = 512;
  }
  for (int z = 4; z < 6; z++) { c1.A[z] = nullptr; c1.Bt[z] = nullptr; c1.C[z] = nullptr; c1.M[z] = 0; c1.lda[z] = 512; }
  gemm_mfma<0, 0><<<dim3(4, ceil_div(ND, 128), 4), 256, 0, stream>>>(c1);

  float* embp[4] = { emb_m, emb_m + 1024, emb_d, emb_d + 1024 };
  GathB g1;
  for (int z = 0; z < 4; z++) {
    g1.rowptr[z] = rp4[z]; g1.col[z] = col4[z]; g1.val[z] = val4[z];
    g1.dis[z] = dis4[z]; g1.h[z] = h4[z]; g1.b[z] = (const float*)d_in[11 + 4 * z];
    g1.out[z] = embp[z]; g1.n[z] = nn4[z];
  }
  gcn_gather_b<<<dim3(ND, 1, 4), 256, 0, stream>>>(g1);

  // -------- conv2 --------
  BGemm c2 = c1;
  for (int z = 0; z < 4; z++) {
    c2.A[z] = embp[z]; c2.Bt[z] = wt + (size_t)(4 + z) * 262144; c2.C[z] = h4[z];
    c2.M[z] = nn4[z]; c2.lda[z] = 2048;
  }
  gemm_mfma<0, 0><<<dim3(4, ceil_div(ND, 128), 4), 256, 0, stream>>>(c2);

  GathB g2 = g1;
  for (int z = 0; z < 4; z++) { g2.b[z] = (const float*)d_in[13 + 4 * z]; g2.out[z] = embp[z] + 512; }
  gcn_gather_b<<<dim3(ND, 1, 4), 256, 0, stream>>>(g2);

  // -------- gather to view layout --------
  GatherB gt;
  gt.emb[0] = emb_m; gt.emb[1] = emb_d; gt.xv[0] = xv_m; gt.xv[1] = xv_d;
  gt.n[0] = NM; gt.n[1] = ND;
  gather_b<<<dim3(ceil_div(ND * 2048, 256), 1, 2), 256, 0, stream>>>(gt);

  // -------- QKV projections (bf16 out) --------
  BGemm qkv;
  unsigned short* qkvc[6] = { Qm, Km, Vm, Qd, Kd, Vd };
  for (int z = 0; z < 6; z++) {
    qkv.A[z] = (z < 3) ? xv_m : xv_d;
    qkv.Bt[z] = wt + (size_t)((z < 3) ? (8 + z) : (12 + z - 3)) * 262144;
    qkv.C[z] = qkvc[z];
    qkv.M[z] = (z < 3) ? 4 * NM : 4 * ND; qkv.lda[z] = 512;
  }
  gemm_mfma<0, 1><<<dim3(4, ceil_div(4 * ND, 128), 6), 256, 0, stream>>>(qkv);

  // -------- attention: split-K partials, then merge into xv (bf16) --------
  AttArgs aa;
  aa.Q[0] = Qm; aa.K[0] = Km; aa.V[0] = Vm; aa.Op[0] = Op_m; aa.ml[0] = ml_m; aa.N[0] = NM;
  aa.Q[1] = Qd; aa.K[1] = Kd; aa.V[1] = Vd; aa.Op[1] = Op_d; aa.ml[1] = ml_d; aa.N[1] = ND;
  attn5_kernel<<<dim3(ceil_div(ND, 128) * KS, 32, 2), 256, 0, stream>>>(aa);

  MergeB mg;
  mg.Op[0] = Op_m; mg.ml[0] = ml_m; mg.O[0] = (unsigned short*)xv_m; mg.N[0] = NM;
  mg.Op[1] = Op_d; mg.ml[1] = ml_d; mg.O[1] = (unsigned short*)xv_d; mg.N[1] = ND;
  attn_merge_b<<<dim3(ceil_div(4 * ND * 128, 256), 1, 2), 256, 0, stream>>>(mg);

  // -------- Wo (bf16 A in) --------
  BGemm wo;
  for (int z = 0; z < 2; z++) {
    wo.A[z] = (z == 0) ? xv_m : xv_d;
    wo.Bt[z] = wt + (size_t)(z == 0 ? 11 : 15) * 262144;
    wo.C[z] = (z == 0) ? mha_m : mha_d;
    wo.M[z] = (z == 0) ? 4 * NM : 4 * ND; wo.lda[z] = 512;
  }
  for (int z = 2; z < 6; z++) { wo.A[z] = nullptr; wo.Bt[z] = nullptr; wo.C[z] = nullptr; wo.M[z] = 0; wo.lda[z] = 512; }
  gemm_mfma<1, 0><<<dim3(4, ceil_div(4 * ND, 128), 2), 256, 0, stream>>>(wo);

  // -------- fuse --------
  FuseB fz;
  fz.mha[0] = mha_m; fz.mha[1] = mha_d;
  fz.fw[0] = (const float*)d_in[30]; fz.fw[1] = (const float*)d_in[36];
  fz.fb[0] = (const float*)d_in[31]; fz.fb[1] = (const float*)d_in[37];
  fz.y[0] = y_m; fz.y[1] = y_d;
  fz.n[0] = NM; fz.n[1] = ND;
  fuse_b<<<dim3(ceil_div(ND * 512, 256), 1, 2), 256, 0, stream>>>(fz);

  // -------- final TN GEMM (f32) --------
  gemm_tn<<<dim3(ceil_div(ND, 64), ceil_div(NM, 64)), 256, 0, stream>>>(
      y_m, y_d, out, NM, ND, 512, NM, ND, ND);
}

// Round 10
// 839.784 us; speedup vs baseline: 1.0104x; 1.0104x over previous
//
#include <hip/hip_runtime.h>
#include <hip/hip_bf16.h>
#include <cmath>

#define NM 1043
#define ND 2166
#define ATT_SC 0.18033688011112042f  // 0.125 * log2(e)

static inline int ceil_div(int a, int b) { return (a + b - 1) / b; }

typedef __attribute__((ext_vector_type(8))) short bf16x8;
typedef __attribute__((ext_vector_type(4))) float f32x4;
typedef __attribute__((ext_vector_type(2))) unsigned int u32x2;
typedef __attribute__((ext_vector_type(4))) unsigned int u32x4;

union U8 { u32x4 u; bf16x8 h; };

// pack 2 f32 -> 2 bf16 (RNE) via compiler casts (lowers to v_cvt_pk_bf16_f32)
__device__ inline unsigned int pk2(float a, float b) {
  union { __hip_bfloat16 h; unsigned short u; } ca, cb;
  ca.h = __float2bfloat16(a);
  cb.h = __float2bfloat16(b);
  return (unsigned int)ca.u | ((unsigned int)cb.u << 16);
}

__device__ inline unsigned short bf1(float a) {
  union { __hip_bfloat16 h; unsigned short u; } c;
  c.h = __float2bfloat16(a);
  return c.u;
}

// ============ weight prep: W[k][n] f32 -> Wt[n][k] bf16 (16 matrices) ========
struct PrepW { const float* W[16]; unsigned short* Wt[16]; };

__global__ __launch_bounds__(256) void prep_w(PrepW p) {
  const int z = blockIdx.z;
  const float* __restrict__ W = p.W[z];
  unsigned short* __restrict__ Wt = p.Wt[z];
  const int n0 = blockIdx.x * 64, k0 = blockIdx.y * 64;
  __shared__ float Ws[64][65];
  const int tid = threadIdx.x;
#pragma unroll
  for (int it = 0; it < 16; it++) {
    int i = it * 256 + tid;
    int k = i >> 6, n = i & 63;
    Ws[k][n] = W[(size_t)(k0 + k) * 512 + n0 + n];
  }
  __syncthreads();
#pragma unroll
  for (int it = 0; it < 16; it++) {
    int i = it * 256 + tid;
    int n = i >> 6, k = i & 63;
    Wt[(size_t)(n0 + n) * 512 + k0 + k] = bf1(Ws[k][n]);
  }
}

// ============ batched MFMA GEMM: C[M,512] = A[M,512] @ W, Bt = W^T bf16 ======
struct BGemm {
  const void* A[6]; const unsigned short* Bt[6]; void* C[6];
  int M[6]; int lda[6]; float cs[6];
};

template<int AIN_BF16, int COUT_BF16>
__global__ __launch_bounds__(256) void gemm_mfma(BGemm g) {
  const int z = blockIdx.z;
  const int M = g.M[z];
  const int bm = blockIdx.y << 7;
  if (bm >= M) return;
  const int bn = blockIdx.x << 7;
  const int lda = g.lda[z];
  const float csc = g.cs[z];
  const char* __restrict__ Ab = (const char*)g.A[z];
  const char* __restrict__ Btb = (const char*)g.Bt[z];

  __shared__ short As_s[128 * 64];
  __shared__ short Bs_s[128 * 64];
  char* asb = (char*)As_s;
  char* bsb = (char*)Bs_s;

  const int tid = threadIdx.x;
  const int lane = tid & 63;
  const int w = tid >> 6;
  const int wm = (w >> 1) << 6, wn = (w & 1) << 6;
  const int fr = lane & 15, kg = lane >> 4;

  f32x4 acc[4][4];
#pragma unroll
  for (int i = 0; i < 4; i++)
#pragma unroll
    for (int j = 0; j < 4; j++) acc[i][j] = (f32x4){0.f, 0.f, 0.f, 0.f};

  for (int kb = 0; kb < 512; kb += 64) {
    __syncthreads();
#pragma unroll
    for (int qi = 0; qi < 4; qi++) {
      int qid = qi * 256 + tid;
      int mm = qid >> 3, qk = qid & 7;
      u32x4 wv = {0u, 0u, 0u, 0u};
      if (bm + mm < M) {
        if (AIN_BF16) {
          wv = *(const u32x4*)(Ab + ((size_t)(bm + mm) * lda + kb + qk * 8) * 2);
        } else {
          const float* ap = (const float*)Ab + (size_t)(bm + mm) * lda + kb + qk * 8;
          float4 f0 = ((const float4*)ap)[0];
          float4 f1 = ((const float4*)ap)[1];
          wv.x = pk2(f0.x, f0.y); wv.y = pk2(f0.z, f0.w);
          wv.z = pk2(f1.x, f1.y); wv.w = pk2(f1.z, f1.w);
        }
      }
      *(u32x4*)(asb + mm * 128 + ((qk * 16) ^ ((mm & 7) << 4))) = wv;
    }
#pragma unroll
    for (int qi = 0; qi < 4; qi++) {
      int qid = qi * 256 + tid;
      int nn = qid >> 3, qk = qid & 7;
      u32x4 bv = *(const u32x4*)(Btb + (((size_t)(bn + nn)) << 10) + (kb + qk * 8) * 2);
      *(u32x4*)(bsb + nn * 128 + ((qk * 16) ^ ((nn & 7) << 4))) = bv;
    }
    __syncthreads();

#pragma unroll
    for (int ks = 0; ks < 2; ks++) {
      bf16x8 af[4], bfv[4];
#pragma unroll
      for (int i = 0; i < 4; i++) {
        int row = wm + i * 16 + fr;
        af[i] = *(const bf16x8*)(asb + row * 128 + (((ks * 64) + kg * 16) ^ ((row & 7) << 4)));
      }
#pragma unroll
      for (int j = 0; j < 4; j++) {
        int row = wn + j * 16 + fr;
        bfv[j] = *(const bf16x8*)(bsb + row * 128 + (((ks * 64) + kg * 16) ^ ((row & 7) << 4)));
      }
#pragma unroll
      for (int i = 0; i < 4; i++)
#pragma unroll
        for (int j = 0; j < 4; j++)
          acc[i][j] = __builtin_amdgcn_mfma_f32_16x16x32_bf16(af[i], bfv[j], acc[i][j], 0, 0, 0);
    }
  }

#pragma unroll
  for (int i = 0; i < 4; i++) {
    int m0 = bm + wm + i * 16 + kg * 4;
#pragma unroll
    for (int j = 0; j < 4; j++) {
      int n = bn + wn + j * 16 + fr;
#pragma unroll
      for (int r = 0; r < 4; r++) {
        if (m0 + r < M) {
          float vv = acc[i][j][r] * csc;
          if (COUT_BF16) ((unsigned short*)g.C[z])[(size_t)(m0 + r) * 512 + n] = bf1(vv);
          else ((float*)g.C[z])[(size_t)(m0 + r) * 512 + n] = vv;
        }
      }
    }
  }
}

// ================= final TN GEMM (f32, unchanged) =================
__global__ __launch_bounds__(256) void gemm_tn(
    const float* __restrict__ A, const float* __restrict__ B, float* __restrict__ C,
    int M, int N, int K, int lda, int ldb, int ldc) {
  __shared__ float As[16][65];
  __shared__ float Bs[16][65];
  const int tid = threadIdx.x;
  const int tx = tid & 15, ty = tid >> 4;
  const int bm = blockIdx.y << 6, bn = blockIdx.x << 6;
  float acc[4][4] = {};
  for (int k0 = 0; k0 < K; k0 += 16) {
    for (int i = tid; i < 16 * 64; i += 256) {
      int kk = i >> 6, mm = i & 63;
      int r = k0 + kk, c = bm + mm;
      As[kk][mm] = (r < K && c < M) ? A[(size_t)r * lda + c] : 0.f;
    }
    for (int i = tid; i < 16 * 64; i += 256) {
      int kk = i >> 6, nn = i & 63;
      int r = k0 + kk, c = bn + nn;
      Bs[kk][nn] = (r < K && c < N) ? B[(size_t)r * ldb + c] : 0.f;
    }
    __syncthreads();
#pragma unroll
    for (int kk = 0; kk < 16; kk++) {
      float a[4], b[4];
#pragma unroll
      for (int i = 0; i < 4; i++) a[i] = As[kk][ty + (i << 4)];
#pragma unroll
      for (int j = 0; j < 4; j++) b[j] = Bs[kk][tx + (j << 4)];
#pragma unroll
      for (int i = 0; i < 4; i++)
#pragma unroll
        for (int j = 0; j < 4; j++) acc[i][j] += a[i] * b[j];
    }
    __syncthreads();
  }
#pragma unroll
  for (int i = 0; i < 4; i++) {
    int r = bm + ty + (i << 4);
    if (r >= M) continue;
#pragma unroll
    for (int j = 0; j < 4; j++) {
      int c = bn + tx + (j << 4);
      if (c < N) C[(size_t)r * ldc + c] = acc[i][j];
    }
  }
}

// ================= GCN: CSR build + fused gather =================
struct DegB {
  const int* dst[4]; const float* attr[4];
  float* dis[4]; int* cnt[4];
  int epref[5];
};

__global__ __launch_bounds__(256) void deg_count_b(DegB g) {
  int et = blockIdx.x * 256 + threadIdx.x;
  if (et >= g.epref[4]) return;
  int z = (et >= g.epref[1]) + (et >= g.epref[2]) + (et >= g.epref[3]);
  int e = et - g.epref[z];
  int d = g.dst[z][e];
  atomicAdd(&g.dis[z][d], g.attr[z][e]);
  atomicAdd(&g.cnt[z][d], 1);
}

struct FinB { float* dis[4]; int n[4]; };

__global__ __launch_bounds__(256) void finish_dis_b(FinB g) {
  int z = blockIdx.z;
  int i = blockIdx.x * 256 + threadIdx.x;
  if (i < g.n[z]) g.dis[z][i] = rsqrtf(g.dis[z][i] + 1.0f);
}

struct ScanB { const int* cnt[4]; int* rowptr[4]; int n[4]; };

__global__ __launch_bounds__(256) void scan_b(ScanB s) {
  int z = blockIdx.x;
  int n = s.n[z];
  const int* cnt = s.cnt[z];
  int* rp = s.rowptr[z];
  __shared__ int sums[256];
  int tid = threadIdx.x;
  int chunk = (n + 255) >> 8;
  int start = tid * chunk;
  int local = 0;
  for (int i = 0; i < chunk; i++) {
    int idx = start + i;
    if (idx < n) local += cnt[idx];
  }
  sums[tid] = local;
  __syncthreads();
  for (int off = 1; off < 256; off <<= 1) {
    int t = (tid >= off) ? sums[tid - off] : 0;
    __syncthreads();
    sums[tid] += t;
    __syncthreads();
  }
  int base = sums[tid] - local;
  int total = sums[255];
  int run = base;
  for (int i = 0; i < chunk; i++) {
    int idx = start + i;
    if (idx < n) { rp[idx] = run; run += cnt[idx]; }
  }
  if (tid == 0) rp[n] = total;
}

struct FillB {
  const int* src[4]; const int* dst[4]; const float* attr[4];
  const int* rowptr[4]; int* cur[4]; int* col[4]; float* val[4];
  int epref[5];
};

__global__ __launch_bounds__(256) void fill_b(FillB f) {
  int et = blockIdx.x * 256 + threadIdx.x;
  if (et >= f.epref[4]) return;
  int z = (et >= f.epref[1]) + (et >= f.epref[2]) + (et >= f.epref[3]);
  int e = et - f.epref[z];
  int d = f.dst[z][e];
  int pos = f.rowptr[z][d] + atomicAdd(&f.cur[z][d], 1);
  f.col[z][pos] = f.src[z][e];
  f.val[z][pos] = f.attr[z][e];
}

struct GathB {
  const int* rowptr[4]; const int* col[4]; const float* val[4];
  const float* dis[4]; const float* h[4]; const float* b[4];
  float* out[4]; int n[4];
};

__global__ __launch_bounds__(256) void gcn_gather_b(GathB c) {
  const int z = blockIdx.z;
  const int node = blockIdx.x;
  if (node >= c.n[z]) return;
  const int tid = threadIdx.x;
  const int* __restrict__ col = c.col[z];
  const float* __restrict__ val = c.val[z];
  const float* __restrict__ dis = c.dis[z];
  const float* __restrict__ h = c.h[z];
  const int beg = c.rowptr[z][node], end = c.rowptr[z][node + 1];
  float acc0 = 0.f, acc1 = 0.f;
  int e = beg;
  for (; e + 4 <= end; e += 4) {
    int s0 = col[e], s1 = col[e + 1], s2 = col[e + 2], s3 = col[e + 3];
    float w0 = val[e] * dis[s0];
    float w1 = val[e + 1] * dis[s1];
    float w2 = val[e + 2] * dis[s2];
    float w3 = val[e + 3] * dis[s3];
    const float* p0 = h + ((size_t)s0 << 9);
    const float* p1 = h + ((size_t)s1 << 9);
    const float* p2 = h + ((size_t)s2 << 9);
    const float* p3 = h + ((size_t)s3 << 9);
    acc0 += w0 * p0[tid] + w1 * p1[tid] + w2 * p2[tid] + w3 * p3[tid];
    acc1 += w0 * p0[tid + 256] + w1 * p1[tid + 256] + w2 * p2[tid + 256] + w3 * p3[tid + 256];
  }
  for (; e < end; e++) {
    int s = col[e];
    float w = val[e] * dis[s];
    const float* p = h + ((size_t)s << 9);
    acc0 += w * p[tid];
    acc1 += w * p[tid + 256];
  }
  const float dd = dis[node];
  const float* hp = h + ((size_t)node << 9);
  float o0 = fmaxf(dd * acc0 + dd * dd * hp[tid] + c.b[z][tid], 0.f);
  float o1 = fmaxf(dd * acc1 + dd * dd * hp[tid + 256] + c.b[z][tid + 256], 0.f);
  float* op = c.out[z] + (size_t)node * 2048;
  op[tid] = o0;
  op[tid + 256] = o1;
}

// ================= view gather =================
struct GatherB { const float* emb[2]; float* xv[2]; int n[2]; };

__global__ __launch_bounds__(256) void gather_b(GatherB g) {
  int z = blockIdx.z;
  int n = g.n[z];
  size_t i = (size_t)blockIdx.x * 256 + threadIdx.x;
  if (i >= (size_t)n * 2048) return;
  int e = (int)(i & 511);
  size_t t = i >> 9;
  int v = (int)(t / n);
  int nn = (int)(t - (size_t)v * n);
  g.xv[z][i] = g.emb[z][((size_t)v * 512 + e) * n + nn];
}

// ================= attention v6: bf16 in/out, exp2 softmax, cvt_pk packing ===
// Q pre-scaled by 0.125*log2(e) at QKV epilogue -> S already in base-2 domain.
struct AttArgs {
  const unsigned short* Q[2]; const unsigned short* K[2]; const unsigned short* V[2];
  unsigned short* O[2]; int N[2];
};

__global__ __launch_bounds__(256) void attn6_kernel(AttArgs ar) {
  const int z = blockIdx.z;
  const int N = ar.N[z];
  const int qb = blockIdx.x * 128;
  if (qb >= N) return;
  const int vh = blockIdx.y, v = vh >> 3, h = vh & 7;
  const size_t base = (size_t)v * N * 512 + (size_t)h * 64;
  const unsigned short* __restrict__ Qb = ar.Q[z] + base;
  const char* __restrict__ Kc = (const char*)(ar.K[z] + base);
  const char* __restrict__ Vc = (const char*)(ar.V[z] + base);
  unsigned short* __restrict__ Ob = ar.O[z] + base;

  __shared__ short kt_s[64 * 64];
  __shared__ short vt_s[64 * 64];
  char* ktb = (char*)kt_s;
  char* vtb = (char*)vt_s;

  const int tid = threadIdx.x;
  const int lane = tid & 63;
  const int w = tid >> 6;
  const int a15 = lane & 15;
  const int g = lane >> 4;

  const int qA = qb + w * 32 + a15;
  const int qB = qA + 16;
  bf16x8 qfA0 = {}, qfA1 = {}, qfB0 = {}, qfB1 = {};
  if (qA < N) {
    qfA0 = *(const bf16x8*)(Qb + (size_t)qA * 512 + g * 8);
    qfA1 = *(const bf16x8*)(Qb + (size_t)qA * 512 + 32 + g * 8);
  }
  if (qB < N) {
    qfB0 = *(const bf16x8*)(Qb + (size_t)qB * 512 + g * 8);
    qfB1 = *(const bf16x8*)(Qb + (size_t)qB * 512 + 32 + g * 8);
  }

  float rmA = -INFINITY, rsA = 0.f, rmB = -INFINITY, rsB = 0.f;
  f32x4 oA0 = {0.f, 0.f, 0.f, 0.f}, oA1 = oA0, oA2 = oA0, oA3 = oA0;
  f32x4 oB0 = oA0, oB1 = oA0, oB2 = oA0, oB3 = oA0;

  const int swzk = (a15 & 7) << 4;
  const int swzv = a15 << 3;
  const int skr = tid >> 2, skq = (tid & 3) * 16;
  const int vsr = tid & 15, vsc = tid >> 4;

  for (int kb = 0; kb < N; kb += 64) {
    __syncthreads();
    // ---- stage K (bf16 copy, swizzled) ----
    {
      const int sw = (skr & 7) << 4;
      const char* kp = Kc + (size_t)(kb + skr) * 1024;
      u32x4 k0 = {0u,0u,0u,0u}, k1 = {0u,0u,0u,0u};
      if (kb + skr < N) {
        k0 = *(const u32x4*)(kp + skq);
        k1 = *(const u32x4*)(kp + skq + 64);
      }
      *(u32x4*)(ktb + skr * 128 + (skq ^ sw)) = k0;
      *(u32x4*)(ktb + skr * 128 + ((skq + 64) ^ sw)) = k1;
    }
    // ---- stage V transposed (register bf16 transpose, swizzled) ----
    {
      const int r0 = kb + 4 * vsr;
      u32x2 i0 = {0u,0u}, i1 = {0u,0u}, i2 = {0u,0u}, i3 = {0u,0u};
      const char* vp = Vc + (size_t)r0 * 1024 + vsc * 8;
      if (r0 + 0 < N) i0 = *(const u32x2*)(vp);
      if (r0 + 1 < N) i1 = *(const u32x2*)(vp + 1024);
      if (r0 + 2 < N) i2 = *(const u32x2*)(vp + 2048);
      if (r0 + 3 < N) i3 = *(const u32x2*)(vp + 3072);
      const int dd = 4 * vsc, kby = 8 * vsr;
      u32x2 o;
      o.x = (i0.x & 0xFFFFu) | (i1.x << 16); o.y = (i2.x & 0xFFFFu) | (i3.x << 16);
      *(u32x2*)(vtb + (dd + 0) * 128 + (kby ^ (((dd + 0) & 15) << 3))) = o;
      o.x = (i0.x >> 16) | (i1.x & 0xFFFF0000u); o.y = (i2.x >> 16) | (i3.x & 0xFFFF0000u);
      *(u32x2*)(vtb + (dd + 1) * 128 + (kby ^ (((dd + 1) & 15) << 3))) = o;
      o.x = (i0.y & 0xFFFFu) | (i1.y << 16); o.y = (i2.y & 0xFFFFu) | (i3.y << 16);
      *(u32x2*)(vtb + (dd + 2) * 128 + (kby ^ (((dd + 2) & 15) << 3))) = o;
      o.x = (i0.y >> 16) | (i1.y & 0xFFFF0000u); o.y = (i2.y >> 16) | (i3.y & 0xFFFF0000u);
      *(u32x2*)(vtb + (dd + 3) * 128 + (kby ^ (((dd + 3) & 15) << 3))) = o;
    }
    __syncthreads();

    // ---- QK^T (K fragments shared between q-tiles) ----
    f32x4 sA0 = {0.f,0.f,0.f,0.f}, sA1 = sA0, sA2 = sA0, sA3 = sA0;
    f32x4 sB0 = sA0, sB1 = sA0, sB2 = sA0, sB3 = sA0;
#define QK2(m, sAm, sBm, s2, qfa, qfb) { \
    bf16x8 kf = *(const bf16x8*)(ktb + (16 * m + a15) * 128 + ((64 * s2 + 16 * g) ^ swzk)); \
    sAm = __builtin_amdgcn_mfma_f32_16x16x32_bf16(kf, qfa, sAm, 0, 0, 0); \
    sBm = __builtin_amdgcn_mfma_f32_16x16x32_bf16(kf, qfb, sBm, 0, 0, 0); }
    QK2(0, sA0, sB0, 0, qfA0, qfB0) QK2(1, sA1, sB1, 0, qfA0, qfB0)
    QK2(2, sA2, sB2, 0, qfA0, qfB0) QK2(3, sA3, sB3, 0, qfA0, qfB0)
    QK2(0, sA0, sB0, 1, qfA1, qfB1) QK2(1, sA1, sB1, 1, qfA1, qfB1)
    QK2(2, sA2, sB2, 1, qfA1, qfB1) QK2(3, sA3, sB3, 1, qfA1, qfB1)
#undef QK2

    if (kb + 64 > N) {
#define MSK(sfm, sgm, m) { int kk = kb + 16 * m + 4 * g; \
      if (kk + 0 >= N) { sfm.x = -INFINITY; sgm.x = -INFINITY; } \
      if (kk + 1 >= N) { sfm.y = -INFINITY; sgm.y = -INFINITY; } \
      if (kk + 2 >= N) { sfm.z = -INFINITY; sgm.z = -INFINITY; } \
      if (kk + 3 >= N) { sfm.w = -INFINITY; sgm.w = -INFINITY; } }
      MSK(sA0, sB0, 0) MSK(sA1, sB1, 1) MSK(sA2, sB2, 2) MSK(sA3, sB3, 3)
#undef MSK
    }

    // ---- online softmax (base-2 domain) + PV ----
#define SMX(sfm, px, py) { \
    float e0 = exp2f(sfm.x - nm), e1 = exp2f(sfm.y - nm); \
    float e2 = exp2f(sfm.z - nm), e3 = exp2f(sfm.w - nm); \
    ps += (e0 + e1) + (e2 + e3); \
    px = pk2(e0, e1); py = pk2(e2, e3); }
#define PV(md, om, s2, pbr) { \
    const char* vr = vtb + (16 * md + a15) * 128; \
    u32x2 v0 = *(const u32x2*)(vr + ((64 * s2 + 8 * g) ^ swzv)); \
    u32x2 v1 = *(const u32x2*)(vr + ((64 * s2 + 32 + 8 * g) ^ swzv)); \
    U8 av; av.u.x = v0.x; av.u.y = v0.y; av.u.z = v1.x; av.u.w = v1.y; \
    om = __builtin_amdgcn_mfma_f32_16x16x32_bf16(av.h, pbr, om, 0, 0, 0); }
#define SOFTMAX_PV(sf0, sf1, sf2, sf3, rm, rs, q0, q1, q2, q3) { \
    float tmax = fmaxf(fmaxf(fmaxf(sf0.x, sf0.y), fmaxf(sf0.z, sf0.w)), \
                       fmaxf(fmaxf(sf1.x, sf1.y), fmaxf(sf1.z, sf1.w))); \
    tmax = fmaxf(tmax, fmaxf(fmaxf(fmaxf(sf2.x, sf2.y), fmaxf(sf2.z, sf2.w)), \
                             fmaxf(fmaxf(sf3.x, sf3.y), fmaxf(sf3.z, sf3.w)))); \
    tmax = fmaxf(tmax, __shfl_xor(tmax, 16)); \
    tmax = fmaxf(tmax, __shfl_xor(tmax, 32)); \
    const float nm = fmaxf(rm, tmax); \
    const float sc = exp2f(rm - nm); \
    float ps = 0.f; \
    U8 pb0, pb1; \
    SMX(sf0, pb0.u.x, pb0.u.y) SMX(sf1, pb0.u.z, pb0.u.w) \
    SMX(sf2, pb1.u.x, pb1.u.y) SMX(sf3, pb1.u.z, pb1.u.w) \
    ps += __shfl_xor(ps, 16); \
    ps += __shfl_xor(ps, 32); \
    rs = rs * sc + ps; \
    rm = nm; \
    q0 *= sc; q1 *= sc; q2 *= sc; q3 *= sc; \
    PV(0, q0, 0, pb0.h) PV(1, q1, 0, pb0.h) PV(2, q2, 0, pb0.h) PV(3, q3, 0, pb0.h) \
    PV(0, q0, 1, pb1.h) PV(1, q1, 1, pb1.h) PV(2, q2, 1, pb1.h) PV(3, q3, 1, pb1.h) }

    SOFTMAX_PV(sA0, sA1, sA2, sA3, rmA, rsA, oA0, oA1, oA2, oA3)
    SOFTMAX_PV(sB0, sB1, sB2, sB3, rmB, rsB, oB0, oB1, oB2, oB3)
#undef SOFTMAX_PV
#undef PV
#undef SMX
  }

  // ---- store O bf16 (row q, d = 16*md + 4g + r) ----
  if (qA < N) {
    const float inv = 1.0f / rsA;
    char* op = (char*)(Ob + (size_t)qA * 512) + g * 8;
    u32x2 r;
    r.x = pk2(oA0.x * inv, oA0.y * inv); r.y = pk2(oA0.z * inv, oA0.w * inv);
    *(u32x2*)(op) = r;
    r.x = pk2(oA1.x * inv, oA1.y * inv); r.y = pk2(oA1.z * inv, oA1.w * inv);
    *(u32x2*)(op + 32) = r;
    r.x = pk2(oA2.x * inv, oA2.y * inv); r.y = pk2(oA2.z * inv, oA2.w * inv);
    *(u32x2*)(op + 64) = r;
    r.x = pk2(oA3.x * inv, oA3.y * inv); r.y = pk2(oA3.z * inv, oA3.w * inv);
    *(u32x2*)(op + 96) = r;
  }
  if (qB < N) {
    const float inv = 1.0f / rsB;
    char* op = (char*)(Ob + (size_t)qB * 512) + g * 8;
    u32x2 r;
    r.x = pk2(oB0.x * inv, oB0.y * inv); r.y = pk2(oB0.z * inv, oB0.w * inv);
    *(u32x2*)(op) = r;
    r.x = pk2(oB1.x * inv, oB1.y * inv); r.y = pk2(oB1.z * inv, oB1.w * inv);
    *(u32x2*)(op + 32) = r;
    r.x = pk2(oB2.x * inv, oB2.y * inv); r.y = pk2(oB2.z * inv, oB2.w * inv);
    *(u32x2*)(op + 64) = r;
    r.x = pk2(oB3.x * inv, oB3.y * inv); r.y = pk2(oB3.z * inv, oB3.w * inv);
    *(u32x2*)(op + 96) = r;
  }
}

// ================= fuse =================
struct FuseB { const float* mha[2]; const float* fw[2]; const float* fb[2]; float* y[2]; int n[2]; };

__global__ __launch_bounds__(256) void fuse_b(FuseB fz) {
  int z = blockIdx.z;
  int n = fz.n[z];
  int i = blockIdx.x * 256 + threadIdx.x;
  if (i >= n * 512) return;
  size_t stride = (size_t)n * 512;
  const float* m = fz.mha[z];
  const float* fw = fz.fw[z];
  float acc = fz.fb[z][0];
  acc += fw[0] * m[i];
  acc += fw[1] * m[stride + i];
  acc += fw[2] * m[2 * stride + i];
  acc += fw[3] * m[3 * stride + i];
  fz.y[z][i] = acc;
}

// ================= launch =================
extern "C" void kernel_launch(void* const* d_in, const int* in_sizes, int n_in,
                              void* d_out, int out_size, void* d_ws, size_t ws_size,
                              hipStream_t stream) {
  const float* mirna_x = (const float*)d_in[0];
  const float* drug_x  = (const float*)d_in[1];
  const int* edge[4] = { (const int*)d_in[2], (const int*)d_in[4], (const int*)d_in[6], (const int*)d_in[8] };
  const float* attr[4] = { (const float*)d_in[3], (const float*)d_in[5], (const float*)d_in[7], (const float*)d_in[9] };
  const int m[4] = { in_sizes[2] / 2, in_sizes[4] / 2, in_sizes[6] / 2, in_sizes[8] / 2 };
  const int nn4[4] = { NM, NM, ND, ND };
  float* out = (float*)d_out;

  float* ws = (float*)d_ws;
  size_t off = 0;
  auto take = [&](size_t nelem) {
    float* r = ws + off;
    off += (nelem + 255) & ~(size_t)255;
    return r;
  };
  const size_t HN = (size_t)NM * 512, HD = (size_t)ND * 512;
  const size_t HALL = 2 * HN + 2 * HD;
  float* emb_m = take((size_t)NM * 2048);
  float* emb_d = take((size_t)ND * 2048);
  float* region = take(2 * HALL);
  float* h4[4] = { region, region + HN, region + 2 * HN, region + 2 * HN + HD };
  float* xv_m = region;
  float* xv_d = region + (size_t)NM * 2048;
  float* dis_all = take(4 * 2560);
  float* dis4[4] = { dis_all, dis_all + 2560, dis_all + 2 * 2560, dis_all + 3 * 2560 };
  int* cnt_all = (int*)take(4 * 2560);
  int* cnt4[4] = { cnt_all, cnt_all + 2560, cnt_all + 2 * 2560, cnt_all + 3 * 2560 };
  int* rp_all = (int*)take(4 * 2304);
  int* rp4[4] = { rp_all, rp_all + 2304, rp_all + 2 * 2304, rp_all + 3 * 2304 };
  int* col4[4];
  float* val4[4];
  for (int z = 0; z < 4; z++) {
    col4[z] = (int*)take(m[z]);
    val4[z] = take(m[z]);
  }
  unsigned short* Qm = (unsigned short*)take((size_t)NM * 1024);
  unsigned short* Km = (unsigned short*)take((size_t)NM * 1024);
  unsigned short* Vm = (unsigned short*)take((size_t)NM * 1024);
  unsigned short* Qd = (unsigned short*)take((size_t)ND * 1024);
  unsigned short* Kd = (unsigned short*)take((size_t)ND * 1024);
  unsigned short* Vd = (unsigned short*)take((size_t)ND * 1024);
  float* mha_m = take((size_t)NM * 2048);
  float* mha_d = take((size_t)ND * 2048);
  float* y_m = take(HN);
  float* y_d = take(HD);
  unsigned short* wt = (unsigned short*)take((size_t)16 * 131072);

  int pref = 0;
  int epref[5];
  for (int z = 0; z < 4; z++) { epref[z] = pref; pref += m[z]; }
  epref[4] = pref;

  // -------- weight prep: 0-3 W1, 4-7 W2, 8-11 mir QKVO, 12-15 drug --------
  PrepW pw;
  for (int z = 0; z < 4; z++) {
    pw.W[z] = (const float*)d_in[10 + 4 * z];
    pw.W[4 + z] = (const float*)d_in[12 + 4 * z];
    pw.W[8 + z] = (const float*)d_in[26 + z];
    pw.W[12 + z] = (const float*)d_in[32 + z];
  }
  for (int z = 0; z < 16; z++) pw.Wt[z] = wt + (size_t)z * 262144;
  prep_w<<<dim3(8, 8, 16), 256, 0, stream>>>(pw);

  // -------- CSR build --------
  hipMemsetAsync(dis_all, 0, 4 * 2560 * sizeof(float), stream);
  hipMemsetAsync(cnt_all, 0, 4 * 2560 * sizeof(int), stream);

  DegB db;
  for (int z = 0; z < 4; z++) {
    db.dst[z] = edge[z] + m[z]; db.attr[z] = attr[z];
    db.dis[z] = dis4[z]; db.cnt[z] = cnt4[z];
  }
  for (int z = 0; z < 5; z++) db.epref[z] = epref[z];
  deg_count_b<<<ceil_div(pref, 256), 256, 0, stream>>>(db);

  FinB fn;
  for (int z = 0; z < 4; z++) { fn.dis[z] = dis4[z]; fn.n[z] = nn4[z]; }
  finish_dis_b<<<dim3(ceil_div(ND, 256), 1, 4), 256, 0, stream>>>(fn);

  ScanB sb;
  for (int z = 0; z < 4; z++) { sb.cnt[z] = cnt4[z]; sb.rowptr[z] = rp4[z]; sb.n[z] = nn4[z]; }
  scan_b<<<4, 256, 0, stream>>>(sb);

  hipMemsetAsync(cnt_all, 0, 4 * 2560 * sizeof(int), stream);
  FillB fl;
  for (int z = 0; z < 4; z++) {
    fl.src[z] = edge[z]; fl.dst[z] = edge[z] + m[z]; fl.attr[z] = attr[z];
    fl.rowptr[z] = rp4[z]; fl.cur[z] = cnt4[z]; fl.col[z] = col4[z]; fl.val[z] = val4[z];
  }
  for (int z = 0; z < 5; z++) fl.epref[z] = epref[z];
  fill_b<<<ceil_div(pref, 256), 256, 0, stream>>>(fl);

  // -------- conv1 --------
  BGemm c1;
  const float* xin[4] = { mirna_x, mirna_x, drug_x, drug_x };
  for (int z = 0; z < 6; z++) c1.cs[z] = 1.0f;
  for (int z = 0; z < 4; z++) {
    c1.A[z] = xin[z]; c1.Bt[z] = wt + (size_t)z * 262144; c1.C[z] = h4[z];
    c1.M[z] = nn4[z]; c1.lda[z] = 512;
  }
  for (int z = 4; z < 6; z++) { c1.A[z] = nullptr; c1.Bt[z] = nullptr; c1.C[z] = nullptr; c1.M[z] = 0; c1.lda[z] = 512; }
  gemm_mfma<0, 0><<<dim3(4, ceil_div(ND, 128), 4), 256, 0, stream>>>(c1);

  float* embp[4] = { emb_m, emb_m + 1024, emb_d, emb_d + 1024 };
  GathB g1;
  for (int z = 0; z < 4; z++) {
    g1.rowptr[z] = rp4[z]; g1.col[z] = col4[z]; g1.val[z] = val4[z];
    g1.dis[z] = dis4[z]; g1.h[z] = h4[z]; g1.b[z] = (const float*)d_in[11 + 4 * z];
    g1.out[z] = embp[z]; g1.n[z] = nn4[z];
  }
  gcn_gather_b<<<dim3(ND, 1, 4), 256, 0, stream>>>(g1);

  // -------- conv2 --------
  BGemm c2 = c1;
  for (int z = 0; z < 4; z++) {
    c2.A[z] = embp[z]; c2.Bt[z] = wt + (size_t)(4 + z) * 262144; c2.C[z] = h4[z];
    c2.M[z] = nn4[z]; c2.lda[z] = 2048;
  }
  gemm_mfma<0, 0><<<dim3(4, ceil_div(ND, 128), 4), 256, 0, stream>>>(c2);

  GathB g2 = g1;
  for (int z = 0; z < 4; z++) { g2.b[z] = (const float*)d_in[13 + 4 * z]; g2.out[z] = embp[z] + 512; }
  gcn_gather_b<<<dim3(ND, 1, 4), 256, 0, stream>>>(g2);

  // -------- gather to view layout --------
  GatherB gt;
  gt.emb[0] = emb_m; gt.emb[1] = emb_d; gt.xv[0] = xv_m; gt.xv[1] = xv_d;
  gt.n[0] = NM; gt.n[1] = ND;
  gather_b<<<dim3(ceil_div(ND * 2048, 256), 1, 2), 256, 0, stream>>>(gt);

  // -------- QKV projections (bf16 out; Q pre-scaled by ATT_SC) --------
  BGemm qkv;
  unsigned short* qkvc[6] = { Qm, Km, Vm, Qd, Kd, Vd };
  for (int z = 0; z < 6; z++) {
    qkv.A[z] = (z < 3) ? xv_m : xv_d;
    qkv.Bt[z] = wt + (size_t)((z < 3) ? (8 + z) : (12 + z - 3)) * 262144;
    qkv.C[z] = qkvc[z];
    qkv.M[z] = (z < 3) ? 4 * NM : 4 * ND; qkv.lda[z] = 512;
    qkv.cs[z] = (z == 0 || z == 3) ? ATT_SC : 1.0f;
  }
  gemm_mfma<0, 1><<<dim3(4, ceil_div(4 * ND, 128), 6), 256, 0, stream>>>(qkv);

  // -------- attention (bf16 in/out, O -> xv buffers as bf16) --------
  AttArgs aa;
  aa.Q[0] = Qm; aa.K[0] = Km; aa.V[0] = Vm; aa.O[0] = (unsigned short*)xv_m; aa.N[0] = NM;
  aa.Q[1] = Qd; aa.K[1] = Kd; aa.V[1] = Vd; aa.O[1] = (unsigned short*)xv_d; aa.N[1] = ND;
  attn6_kernel<<<dim3(ceil_div(ND, 128), 32, 2), 256, 0, stream>>>(aa);

  // -------- Wo (bf16 A in) --------
  BGemm wo;
  for (int z = 0; z < 6; z++) wo.cs[z] = 1.0f;
  for (int z = 0; z < 2; z++) {
    wo.A[z] = (z == 0) ? xv_m : xv_d;
    wo.Bt[z] = wt + (size_t)(z == 0 ? 11 : 15) * 262144;
    wo.C[z] = (z == 0) ? mha_m : mha_d;
    wo.M[z] = (z == 0) ? 4 * NM : 4 * ND; wo.lda[z] = 512;
  }
  for (int z = 2; z < 6; z++) { wo.A[z] = nullptr; wo.Bt[z] = nullptr; wo.C[z] = nullptr; wo.M[z] = 0; wo.lda[z] = 512; }
  gemm_mfma<1, 0><<<dim3(4, ceil_div(4 * ND, 128), 2), 256, 0, stream>>>(wo);

  // -------- fuse --------
  FuseB fz;
  fz.mha[0] = mha_m; fz.mha[1] = mha_d;
  fz.fw[0] = (const float*)d_in[30]; fz.fw[1] = (const float*)d_in[36];
  fz.fb[0] = (const float*)d_in[31]; fz.fb[1] = (const float*)d_in[37];
  fz.y[0] = y_m; fz.y[1] = y_d;
  fz.n[0] = NM; fz.n[1] = ND;
  fuse_b<<<dim3(ceil_div(ND * 512, 256), 1, 2), 256, 0, stream>>>(fz);

  // -------- final TN GEMM (f32) --------
  gemm_tn<<<dim3(ceil_div(ND, 64), ceil_div(NM, 64)), 256, 0, stream>>>(
      y_m, y_d, out, NM, ND, 512, NM, ND, ND);
}

// Round 11
// 724.046 us; speedup vs baseline: 1.1719x; 1.1598x over previous
//
#include <hip/hip_runtime.h>
#include <hip/hip_bf16.h>
#include <cmath>

#define NM 1043
#define ND 2166
#define ATT_SC 0.18033688011112042f  // 0.125 * log2(e)

static inline int ceil_div(int a, int b) { return (a + b - 1) / b; }

typedef __attribute__((ext_vector_type(8))) short bf16x8;
typedef __attribute__((ext_vector_type(4))) float f32x4;
typedef __attribute__((ext_vector_type(2))) unsigned int u32x2;
typedef __attribute__((ext_vector_type(4))) unsigned int u32x4;

union U8 { u32x4 u; bf16x8 h; };

__device__ inline unsigned int pk2(float a, float b) {
  union { __hip_bfloat16 h; unsigned short u; } ca, cb;
  ca.h = __float2bfloat16(a);
  cb.h = __float2bfloat16(b);
  return (unsigned int)ca.u | ((unsigned int)cb.u << 16);
}

__device__ inline unsigned short bf1(float a) {
  union { __hip_bfloat16 h; unsigned short u; } c;
  c.h = __float2bfloat16(a);
  return c.u;
}

// ============ weight prep: W[k][n] f32 -> Wt[n][k] bf16 (16 matrices) ========
struct PrepW { const float* W[16]; unsigned short* Wt[16]; };

__global__ __launch_bounds__(256) void prep_w(PrepW p) {
  const int z = blockIdx.z;
  const float* __restrict__ W = p.W[z];
  unsigned short* __restrict__ Wt = p.Wt[z];
  const int n0 = blockIdx.x * 64, k0 = blockIdx.y * 64;
  __shared__ float Ws[64][65];
  const int tid = threadIdx.x;
#pragma unroll
  for (int it = 0; it < 16; it++) {
    int i = it * 256 + tid;
    int k = i >> 6, n = i & 63;
    Ws[k][n] = W[(size_t)(k0 + k) * 512 + n0 + n];
  }
  __syncthreads();
#pragma unroll
  for (int it = 0; it < 16; it++) {
    int i = it * 256 + tid;
    int n = i >> 6, k = i & 63;
    Wt[(size_t)(n0 + n) * 512 + k0 + k] = bf1(Ws[k][n]);
  }
}

// ============ y transpose: yflat[k*N+i] f32 -> yT[i*512+k] bf16 ==============
struct PrepYT { const float* y[2]; unsigned short* yT[2]; int n[2]; };

__global__ __launch_bounds__(256) void prep_yt(PrepYT p) {
  const int z = blockIdx.z;
  const int n = p.n[z];
  const int i0 = blockIdx.x * 64, k0 = blockIdx.y * 64;
  if (i0 >= n) return;
  const float* __restrict__ y = p.y[z];
  unsigned short* __restrict__ yT = p.yT[z];
  __shared__ float T[64][65];
  const int tid = threadIdx.x;
#pragma unroll
  for (int it = 0; it < 16; it++) {
    int idx = it * 256 + tid;
    int kk = idx >> 6, ii = idx & 63;
    T[kk][ii] = (i0 + ii < n) ? y[(size_t)(k0 + kk) * n + i0 + ii] : 0.f;
  }
  __syncthreads();
#pragma unroll
  for (int it = 0; it < 16; it++) {
    int idx = it * 256 + tid;
    int ii = idx >> 6, kk = idx & 63;
    if (i0 + ii < n) yT[(size_t)(i0 + ii) * 512 + k0 + kk] = bf1(T[kk][ii]);
  }
}

// ============ batched MFMA GEMM: C[M,512] = A[M,512] @ W, Bt = W^T bf16 ======
struct BGemm {
  const void* A[6]; const unsigned short* Bt[6]; void* C[6];
  int M[6]; int lda[6]; float cs[6];
};

template<int AIN_BF16, int COUT_BF16>
__global__ __launch_bounds__(256) void gemm_mfma(BGemm g) {
  const int z = blockIdx.z;
  const int M = g.M[z];
  const int bm = blockIdx.y << 7;
  if (bm >= M) return;
  const int bn = blockIdx.x << 7;
  const int lda = g.lda[z];
  const float csc = g.cs[z];
  const char* __restrict__ Ab = (const char*)g.A[z];
  const char* __restrict__ Btb = (const char*)g.Bt[z];

  __shared__ short As_s[128 * 64];
  __shared__ short Bs_s[128 * 64];
  char* asb = (char*)As_s;
  char* bsb = (char*)Bs_s;

  const int tid = threadIdx.x;
  const int lane = tid & 63;
  const int w = tid >> 6;
  const int wm = (w >> 1) << 6, wn = (w & 1) << 6;
  const int fr = lane & 15, kg = lane >> 4;

  f32x4 acc[4][4];
#pragma unroll
  for (int i = 0; i < 4; i++)
#pragma unroll
    for (int j = 0; j < 4; j++) acc[i][j] = (f32x4){0.f, 0.f, 0.f, 0.f};

  for (int kb = 0; kb < 512; kb += 64) {
    __syncthreads();
#pragma unroll
    for (int qi = 0; qi < 4; qi++) {
      int qid = qi * 256 + tid;
      int mm = qid >> 3, qk = qid & 7;
      u32x4 wv = {0u, 0u, 0u, 0u};
      if (bm + mm < M) {
        if (AIN_BF16) {
          wv = *(const u32x4*)(Ab + ((size_t)(bm + mm) * lda + kb + qk * 8) * 2);
        } else {
          const float* ap = (const float*)Ab + (size_t)(bm + mm) * lda + kb + qk * 8;
          float4 f0 = ((const float4*)ap)[0];
          float4 f1 = ((const float4*)ap)[1];
          wv.x = pk2(f0.x, f0.y); wv.y = pk2(f0.z, f0.w);
          wv.z = pk2(f1.x, f1.y); wv.w = pk2(f1.z, f1.w);
        }
      }
      *(u32x4*)(asb + mm * 128 + ((qk * 16) ^ ((mm & 7) << 4))) = wv;
    }
#pragma unroll
    for (int qi = 0; qi < 4; qi++) {
      int qid = qi * 256 + tid;
      int nn = qid >> 3, qk = qid & 7;
      u32x4 bv = *(const u32x4*)(Btb + (((size_t)(bn + nn)) << 10) + (kb + qk * 8) * 2);
      *(u32x4*)(bsb + nn * 128 + ((qk * 16) ^ ((nn & 7) << 4))) = bv;
    }
    __syncthreads();

#pragma unroll
    for (int ks = 0; ks < 2; ks++) {
      bf16x8 af[4], bfv[4];
#pragma unroll
      for (int i = 0; i < 4; i++) {
        int row = wm + i * 16 + fr;
        af[i] = *(const bf16x8*)(asb + row * 128 + (((ks * 64) + kg * 16) ^ ((row & 7) << 4)));
      }
#pragma unroll
      for (int j = 0; j < 4; j++) {
        int row = wn + j * 16 + fr;
        bfv[j] = *(const bf16x8*)(bsb + row * 128 + (((ks * 64) + kg * 16) ^ ((row & 7) << 4)));
      }
#pragma unroll
      for (int i = 0; i < 4; i++)
#pragma unroll
        for (int j = 0; j < 4; j++)
          acc[i][j] = __builtin_amdgcn_mfma_f32_16x16x32_bf16(af[i], bfv[j], acc[i][j], 0, 0, 0);
    }
  }

#pragma unroll
  for (int i = 0; i < 4; i++) {
    int m0 = bm + wm + i * 16 + kg * 4;
#pragma unroll
    for (int j = 0; j < 4; j++) {
      int n = bn + wn + j * 16 + fr;
#pragma unroll
      for (int r = 0; r < 4; r++) {
        if (m0 + r < M) {
          float vv = acc[i][j][r] * csc;
          if (COUT_BF16) ((unsigned short*)g.C[z])[(size_t)(m0 + r) * 512 + n] = bf1(vv);
          else ((float*)g.C[z])[(size_t)(m0 + r) * 512 + n] = vv;
        }
      }
    }
  }
}

// ============ final TN GEMM, MFMA: C[M,N] = yTm[M,512] . yTd[N,512]^T ========
__global__ __launch_bounds__(256) void gemm_tn2(const unsigned short* __restrict__ Am,
                                                const unsigned short* __restrict__ Bn,
                                                float* __restrict__ C, int M, int N) {
  const int bm = blockIdx.y << 7;
  const int bn = blockIdx.x << 7;
  __shared__ short As_s[128 * 64];
  __shared__ short Bs_s[128 * 64];
  char* asb = (char*)As_s;
  char* bsb = (char*)Bs_s;
  const int tid = threadIdx.x;
  const int lane = tid & 63;
  const int w = tid >> 6;
  const int wm = (w >> 1) << 6, wn = (w & 1) << 6;
  const int fr = lane & 15, kg = lane >> 4;

  f32x4 acc[4][4];
#pragma unroll
  for (int i = 0; i < 4; i++)
#pragma unroll
    for (int j = 0; j < 4; j++) acc[i][j] = (f32x4){0.f, 0.f, 0.f, 0.f};

  for (int kb = 0; kb < 512; kb += 64) {
    __syncthreads();
#pragma unroll
    for (int qi = 0; qi < 4; qi++) {
      int qid = qi * 256 + tid;
      int mm = qid >> 3, qk = qid & 7;
      u32x4 wv = {0u, 0u, 0u, 0u};
      if (bm + mm < M)
        wv = *(const u32x4*)((const char*)Am + ((size_t)(bm + mm) * 512 + kb + qk * 8) * 2);
      *(u32x4*)(asb + mm * 128 + ((qk * 16) ^ ((mm & 7) << 4))) = wv;
    }
#pragma unroll
    for (int qi = 0; qi < 4; qi++) {
      int qid = qi * 256 + tid;
      int nn = qid >> 3, qk = qid & 7;
      u32x4 bv = {0u, 0u, 0u, 0u};
      if (bn + nn < N)
        bv = *(const u32x4*)((const char*)Bn + ((size_t)(bn + nn) * 512 + kb + qk * 8) * 2);
      *(u32x4*)(bsb + nn * 128 + ((qk * 16) ^ ((nn & 7) << 4))) = bv;
    }
    __syncthreads();

#pragma unroll
    for (int ks = 0; ks < 2; ks++) {
      bf16x8 af[4], bfv[4];
#pragma unroll
      for (int i = 0; i < 4; i++) {
        int row = wm + i * 16 + fr;
        af[i] = *(const bf16x8*)(asb + row * 128 + (((ks * 64) + kg * 16) ^ ((row & 7) << 4)));
      }
#pragma unroll
      for (int j = 0; j < 4; j++) {
        int row = wn + j * 16 + fr;
        bfv[j] = *(const bf16x8*)(bsb + row * 128 + (((ks * 64) + kg * 16) ^ ((row & 7) << 4)));
      }
#pragma unroll
      for (int i = 0; i < 4; i++)
#pragma unroll
        for (int j = 0; j < 4; j++)
          acc[i][j] = __builtin_amdgcn_mfma_f32_16x16x32_bf16(af[i], bfv[j], acc[i][j], 0, 0, 0);
    }
  }

#pragma unroll
  for (int i = 0; i < 4; i++) {
    int m0 = bm + wm + i * 16 + kg * 4;
#pragma unroll
    for (int j = 0; j < 4; j++) {
      int n = bn + wn + j * 16 + fr;
      if (n >= N) continue;
#pragma unroll
      for (int r = 0; r < 4; r++) {
        if (m0 + r < M) C[(size_t)(m0 + r) * N + n] = acc[i][j][r];
      }
    }
  }
}

// ================= GCN: CSR build + fused gather =================
struct DegB {
  const int* dst[4]; const float* attr[4];
  float* dis[4]; int* cnt[4];
  int epref[5];
};

__global__ __launch_bounds__(256) void deg_count_b(DegB g) {
  int et = blockIdx.x * 256 + threadIdx.x;
  if (et >= g.epref[4]) return;
  int z = (et >= g.epref[1]) + (et >= g.epref[2]) + (et >= g.epref[3]);
  int e = et - g.epref[z];
  int d = g.dst[z][e];
  atomicAdd(&g.dis[z][d], g.attr[z][e]);
  atomicAdd(&g.cnt[z][d], 1);
}

struct FinB { float* dis[4]; int n[4]; };

__global__ __launch_bounds__(256) void finish_dis_b(FinB g) {
  int z = blockIdx.z;
  int i = blockIdx.x * 256 + threadIdx.x;
  if (i < g.n[z]) g.dis[z][i] = rsqrtf(g.dis[z][i] + 1.0f);
}

struct ScanB { const int* cnt[4]; int* rowptr[4]; int n[4]; };

__global__ __launch_bounds__(256) void scan_b(ScanB s) {
  int z = blockIdx.x;
  int n = s.n[z];
  const int* cnt = s.cnt[z];
  int* rp = s.rowptr[z];
  __shared__ int sums[256];
  int tid = threadIdx.x;
  int chunk = (n + 255) >> 8;
  int start = tid * chunk;
  int local = 0;
  for (int i = 0; i < chunk; i++) {
    int idx = start + i;
    if (idx < n) local += cnt[idx];
  }
  sums[tid] = local;
  __syncthreads();
  for (int off = 1; off < 256; off <<= 1) {
    int t = (tid >= off) ? sums[tid - off] : 0;
    __syncthreads();
    sums[tid] += t;
    __syncthreads();
  }
  int base = sums[tid] - local;
  int total = sums[255];
  int run = base;
  for (int i = 0; i < chunk; i++) {
    int idx = start + i;
    if (idx < n) { rp[idx] = run; run += cnt[idx]; }
  }
  if (tid == 0) rp[n] = total;
}

struct FillB {
  const int* src[4]; const int* dst[4]; const float* attr[4];
  const int* rowptr[4]; int* cur[4]; int* col[4]; float* val[4];
  int epref[5];
};

__global__ __launch_bounds__(256) void fill_b(FillB f) {
  int et = blockIdx.x * 256 + threadIdx.x;
  if (et >= f.epref[4]) return;
  int z = (et >= f.epref[1]) + (et >= f.epref[2]) + (et >= f.epref[3]);
  int e = et - f.epref[z];
  int d = f.dst[z][e];
  int pos = f.rowptr[z][d] + atomicAdd(&f.cur[z][d], 1);
  f.col[z][pos] = f.src[z][e];
  f.val[z][pos] = f.attr[z][e];
}

struct GathB {
  const int* rowptr[4]; const int* col[4]; const float* val[4];
  const float* dis[4]; const float* h[4]; const float* b[4];
  float* out[4]; int n[4];
};

__global__ __launch_bounds__(256) void gcn_gather_b(GathB c) {
  const int z = blockIdx.z;
  const int node = blockIdx.x;
  if (node >= c.n[z]) return;
  const int tid = threadIdx.x;
  const int* __restrict__ col = c.col[z];
  const float* __restrict__ val = c.val[z];
  const float* __restrict__ dis = c.dis[z];
  const float* __restrict__ h = c.h[z];
  const int beg = c.rowptr[z][node], end = c.rowptr[z][node + 1];
  float acc0 = 0.f, acc1 = 0.f;
  int e = beg;
  for (; e + 4 <= end; e += 4) {
    int s0 = col[e], s1 = col[e + 1], s2 = col[e + 2], s3 = col[e + 3];
    float w0 = val[e] * dis[s0];
    float w1 = val[e + 1] * dis[s1];
    float w2 = val[e + 2] * dis[s2];
    float w3 = val[e + 3] * dis[s3];
    const float* p0 = h + ((size_t)s0 << 9);
    const float* p1 = h + ((size_t)s1 << 9);
    const float* p2 = h + ((size_t)s2 << 9);
    const float* p3 = h + ((size_t)s3 << 9);
    acc0 += w0 * p0[tid] + w1 * p1[tid] + w2 * p2[tid] + w3 * p3[tid];
    acc1 += w0 * p0[tid + 256] + w1 * p1[tid + 256] + w2 * p2[tid + 256] + w3 * p3[tid + 256];
  }
  for (; e < end; e++) {
    int s = col[e];
    float w = val[e] * dis[s];
    const float* p = h + ((size_t)s << 9);
    acc0 += w * p[tid];
    acc1 += w * p[tid + 256];
  }
  const float dd = dis[node];
  const float* hp = h + ((size_t)node << 9);
  float o0 = fmaxf(dd * acc0 + dd * dd * hp[tid] + c.b[z][tid], 0.f);
  float o1 = fmaxf(dd * acc1 + dd * dd * hp[tid + 256] + c.b[z][tid + 256], 0.f);
  float* op = c.out[z] + (size_t)node * 2048;
  op[tid] = o0;
  op[tid + 256] = o1;
}

// ================= view gather =================
struct GatherB { const float* emb[2]; float* xv[2]; int n[2]; };

__global__ __launch_bounds__(256) void gather_b(GatherB g) {
  int z = blockIdx.z;
  int n = g.n[z];
  size_t i = (size_t)blockIdx.x * 256 + threadIdx.x;
  if (i >= (size_t)n * 2048) return;
  int e = (int)(i & 511);
  size_t t = i >> 9;
  int v = (int)(t / n);
  int nn = (int)(t - (size_t)v * n);
  g.xv[z][i] = g.emb[z][((size_t)v * 512 + e) * n + nn];
}

// ===== attention v7: bf16, exp2 softmax, double-buffered K/V + early loads ===
struct AttArgs {
  const unsigned short* Q[2]; const unsigned short* K[2]; const unsigned short* V[2];
  unsigned short* O[2]; int N[2];
};

__global__ __launch_bounds__(256) void attn7_kernel(AttArgs ar) {
  const int z = blockIdx.z;
  const int N = ar.N[z];
  const int qb = blockIdx.x * 128;
  if (qb >= N) return;
  const int vh = blockIdx.y, v = vh >> 3, h = vh & 7;
  const size_t base = (size_t)v * N * 512 + (size_t)h * 64;
  const unsigned short* __restrict__ Qb = ar.Q[z] + base;
  const char* __restrict__ Kc = (const char*)(ar.K[z] + base);
  const char* __restrict__ Vc = (const char*)(ar.V[z] + base);
  unsigned short* __restrict__ Ob = ar.O[z] + base;

  __shared__ short kt_s[2][64 * 64];
  __shared__ short vt_s[2][64 * 64];

  const int tid = threadIdx.x;
  const int lane = tid & 63;
  const int w = tid >> 6;
  const int a15 = lane & 15;
  const int g = tid >> 4 & 3;  // lane>>4 (same for all waves)

  const int qA = qb + w * 32 + a15;
  const int qB = qA + 16;
  bf16x8 qfA0 = {}, qfA1 = {}, qfB0 = {}, qfB1 = {};
  if (qA < N) {
    qfA0 = *(const bf16x8*)(Qb + (size_t)qA * 512 + g * 8);
    qfA1 = *(const bf16x8*)(Qb + (size_t)qA * 512 + 32 + g * 8);
  }
  if (qB < N) {
    qfB0 = *(const bf16x8*)(Qb + (size_t)qB * 512 + g * 8);
    qfB1 = *(const bf16x8*)(Qb + (size_t)qB * 512 + 32 + g * 8);
  }

  float rmA = -INFINITY, rsA = 0.f, rmB = -INFINITY, rsB = 0.f;
  f32x4 oA0 = {0.f, 0.f, 0.f, 0.f}, oA1 = oA0, oA2 = oA0, oA3 = oA0;
  f32x4 oB0 = oA0, oB1 = oA0, oB2 = oA0, oB3 = oA0;

  const int swzk = (a15 & 7) << 4;
  const int swzv = a15 << 3;
  const int skr = tid >> 2, skq = (tid & 3) * 16;
  const int vsr = tid & 15, vsc = tid >> 4;

  // staging registers (tile in flight)
  u32x4 k0r = {0u,0u,0u,0u}, k1r = {0u,0u,0u,0u};
  u32x2 v0r = {0u,0u}, v1r = {0u,0u}, v2r = {0u,0u}, v3r = {0u,0u};

  auto load_tile = [&](int kb) {
    k0r = (u32x4){0u,0u,0u,0u}; k1r = k0r;
    if (kb + skr < N) {
      const char* kp = Kc + (size_t)(kb + skr) * 1024;
      k0r = *(const u32x4*)(kp + skq);
      k1r = *(const u32x4*)(kp + skq + 64);
    }
    const int r0 = kb + 4 * vsr;
    const char* vp = Vc + (size_t)r0 * 1024 + vsc * 8;
    v0r = (u32x2){0u,0u}; v1r = v0r; v2r = v0r; v3r = v0r;
    if (r0 + 0 < N) v0r = *(const u32x2*)(vp);
    if (r0 + 1 < N) v1r = *(const u32x2*)(vp + 1024);
    if (r0 + 2 < N) v2r = *(const u32x2*)(vp + 2048);
    if (r0 + 3 < N) v3r = *(const u32x2*)(vp + 3072);
  };
  auto write_tile = [&](int buf) {
    char* ktb = (char*)kt_s[buf];
    char* vtb = (char*)vt_s[buf];
    const int sw = (skr & 7) << 4;
    *(u32x4*)(ktb + skr * 128 + (skq ^ sw)) = k0r;
    *(u32x4*)(ktb + skr * 128 + ((skq + 64) ^ sw)) = k1r;
    const int dd = 4 * vsc, kby = 8 * vsr;
    u32x2 o;
    o.x = (v0r.x & 0xFFFFu) | (v1r.x << 16); o.y = (v2r.x & 0xFFFFu) | (v3r.x << 16);
    *(u32x2*)(vtb + (dd + 0) * 128 + (kby ^ (((dd + 0) & 15) << 3))) = o;
    o.x = (v0r.x >> 16) | (v1r.x & 0xFFFF0000u); o.y = (v2r.x >> 16) | (v3r.x & 0xFFFF0000u);
    *(u32x2*)(vtb + (dd + 1) * 128 + (kby ^ (((dd + 1) & 15) << 3))) = o;
    o.x = (v0r.y & 0xFFFFu) | (v1r.y << 16); o.y = (v2r.y & 0xFFFFu) | (v3r.y << 16);
    *(u32x2*)(vtb + (dd + 2) * 128 + (kby ^ (((dd + 2) & 15) << 3))) = o;
    o.x = (v0r.y >> 16) | (v1r.y & 0xFFFF0000u); o.y = (v2r.y >> 16) | (v3r.y & 0xFFFF0000u);
    *(u32x2*)(vtb + (dd + 3) * 128 + (kby ^ (((dd + 3) & 15) << 3))) = o;
  };

  const int nt = (N + 63) >> 6;
  load_tile(0);
  write_tile(0);
  __syncthreads();

  for (int t = 0; t < nt; t++) {
    const int kb = t << 6;
    if (t + 1 < nt) load_tile(kb + 64);  // issue next-tile loads (no wait)

    const char* ktb = (const char*)kt_s[t & 1];
    const char* vtb = (const char*)vt_s[t & 1];

    // ---- QK^T (K fragments shared between q-tiles) ----
    f32x4 sA0 = {0.f,0.f,0.f,0.f}, sA1 = sA0, sA2 = sA0, sA3 = sA0;
    f32x4 sB0 = sA0, sB1 = sA0, sB2 = sA0, sB3 = sA0;
#define QK2(m, sAm, sBm, s2, qfa, qfb) { \
    bf16x8 kf = *(const bf16x8*)(ktb + (16 * m + a15) * 128 + ((64 * s2 + 16 * g) ^ swzk)); \
    sAm = __builtin_amdgcn_mfma_f32_16x16x32_bf16(kf, qfa, sAm, 0, 0, 0); \
    sBm = __builtin_amdgcn_mfma_f32_16x16x32_bf16(kf, qfb, sBm, 0, 0, 0); }
    QK2(0, sA0, sB0, 0, qfA0, qfB0) QK2(1, sA1, sB1, 0, qfA0, qfB0)
    QK2(2, sA2, sB2, 0, qfA0, qfB0) QK2(3, sA3, sB3, 0, qfA0, qfB0)
    QK2(0, sA0, sB0, 1, qfA1, qfB1) QK2(1, sA1, sB1, 1, qfA1, qfB1)
    QK2(2, sA2, sB2, 1, qfA1, qfB1) QK2(3, sA3, sB3, 1, qfA1, qfB1)
#undef QK2

    if (kb + 64 > N) {
#define MSK(sfm, sgm, m) { int kk = kb + 16 * m + 4 * g; \
      if (kk + 0 >= N) { sfm.x = -INFINITY; sgm.x = -INFINITY; } \
      if (kk + 1 >= N) { sfm.y = -INFINITY; sgm.y = -INFINITY; } \
      if (kk + 2 >= N) { sfm.z = -INFINITY; sgm.z = -INFINITY; } \
      if (kk + 3 >= N) { sfm.w = -INFINITY; sgm.w = -INFINITY; } }
      MSK(sA0, sB0, 0) MSK(sA1, sB1, 1) MSK(sA2, sB2, 2) MSK(sA3, sB3, 3)
#undef MSK
    }

#define SMX(sfm, px, py) { \
    float e0 = exp2f(sfm.x - nm), e1 = exp2f(sfm.y - nm); \
    float e2 = exp2f(sfm.z - nm), e3 = exp2f(sfm.w - nm); \
    ps += (e0 + e1) + (e2 + e3); \
    px = pk2(e0, e1); py = pk2(e2, e3); }
#define PV(md, om, s2, pbr) { \
    const char* vr = vtb + (16 * md + a15) * 128; \
    u32x2 v0 = *(const u32x2*)(vr + ((64 * s2 + 8 * g) ^ swzv)); \
    u32x2 v1 = *(const u32x2*)(vr + ((64 * s2 + 32 + 8 * g) ^ swzv)); \
    U8 av; av.u.x = v0.x; av.u.y = v0.y; av.u.z = v1.x; av.u.w = v1.y; \
    om = __builtin_amdgcn_mfma_f32_16x16x32_bf16(av.h, pbr, om, 0, 0, 0); }
#define SOFTMAX_PV(sf0, sf1, sf2, sf3, rm, rs, q0, q1, q2, q3) { \
    float tmax = fmaxf(fmaxf(fmaxf(sf0.x, sf0.y), fmaxf(sf0.z, sf0.w)), \
                       fmaxf(fmaxf(sf1.x, sf1.y), fmaxf(sf1.z, sf1.w))); \
    tmax = fmaxf(tmax, fmaxf(fmaxf(fmaxf(sf2.x, sf2.y), fmaxf(sf2.z, sf2.w)), \
                             fmaxf(fmaxf(sf3.x, sf3.y), fmaxf(sf3.z, sf3.w)))); \
    tmax = fmaxf(tmax, __shfl_xor(tmax, 16)); \
    tmax = fmaxf(tmax, __shfl_xor(tmax, 32)); \
    const float nm = fmaxf(rm, tmax); \
    const float sc = exp2f(rm - nm); \
    float ps = 0.f; \
    U8 pb0, pb1; \
    SMX(sf0, pb0.u.x, pb0.u.y) SMX(sf1, pb0.u.z, pb0.u.w) \
    SMX(sf2, pb1.u.x, pb1.u.y) SMX(sf3, pb1.u.z, pb1.u.w) \
    ps += __shfl_xor(ps, 16); \
    ps += __shfl_xor(ps, 32); \
    rs = rs * sc + ps; \
    rm = nm; \
    q0 *= sc; q1 *= sc; q2 *= sc; q3 *= sc; \
    PV(0, q0, 0, pb0.h) PV(1, q1, 0, pb0.h) PV(2, q2, 0, pb0.h) PV(3, q3, 0, pb0.h) \
    PV(0, q0, 1, pb1.h) PV(1, q1, 1, pb1.h) PV(2, q2, 1, pb1.h) PV(3, q3, 1, pb1.h) }

    SOFTMAX_PV(sA0, sA1, sA2, sA3, rmA, rsA, oA0, oA1, oA2, oA3)
    SOFTMAX_PV(sB0, sB1, sB2, sB3, rmB, rsB, oB0, oB1, oB2, oB3)
#undef SOFTMAX_PV
#undef PV
#undef SMX

    __syncthreads();                    // all waves done reading buf[(t+1)&1] (from t-1)
    if (t + 1 < nt) {
      write_tile((t + 1) & 1);          // vmcnt wait lands here, hidden by compute above
      __syncthreads();                  // writes visible before next compute
    }
  }

  // ---- store O bf16 (row q, d = 16*md + 4g + r) ----
  if (qA < N) {
    const float inv = 1.0f / rsA;
    char* op = (char*)(Ob + (size_t)qA * 512) + g * 8;
    u32x2 r;
    r.x = pk2(oA0.x * inv, oA0.y * inv); r.y = pk2(oA0.z * inv, oA0.w * inv);
    *(u32x2*)(op) = r;
    r.x = pk2(oA1.x * inv, oA1.y * inv); r.y = pk2(oA1.z * inv, oA1.w * inv);
    *(u32x2*)(op + 32) = r;
    r.x = pk2(oA2.x * inv, oA2.y * inv); r.y = pk2(oA2.z * inv, oA2.w * inv);
    *(u32x2*)(op + 64) = r;
    r.x = pk2(oA3.x * inv, oA3.y * inv); r.y = pk2(oA3.z * inv, oA3.w * inv);
    *(u32x2*)(op + 96) = r;
  }
  if (qB < N) {
    const float inv = 1.0f / rsB;
    char* op = (char*)(Ob + (size_t)qB * 512) + g * 8;
    u32x2 r;
    r.x = pk2(oB0.x * inv, oB0.y * inv); r.y = pk2(oB0.z * inv, oB0.w * inv);
    *(u32x2*)(op) = r;
    r.x = pk2(oB1.x * inv, oB1.y * inv); r.y = pk2(oB1.z * inv, oB1.w * inv);
    *(u32x2*)(op + 32) = r;
    r.x = pk2(oB2.x * inv, oB2.y * inv); r.y = pk2(oB2.z * inv, oB2.w * inv);
    *(u32x2*)(op + 64) = r;
    r.x = pk2(oB3.x * inv, oB3.y * inv); r.y = pk2(oB3.z * inv, oB3.w * inv);
    *(u32x2*)(op + 96) = r;
  }
}

// ================= fuse =================
struct FuseB { const float* mha[2]; const float* fw[2]; const float* fb[2]; float* y[2]; int n[2]; };

__global__ __launch_bounds__(256) void fuse_b(FuseB fz) {
  int z = blockIdx.z;
  int n = fz.n[z];
  int i = blockIdx.x * 256 + threadIdx.x;
  if (i >= n * 512) return;
  size_t stride = (size_t)n * 512;
  const float* m = fz.mha[z];
  const float* fw = fz.fw[z];
  float acc = fz.fb[z][0];
  acc += fw[0] * m[i];
  acc += fw[1] * m[stride + i];
  acc += fw[2] * m[2 * stride + i];
  acc += fw[3] * m[3 * stride + i];
  fz.y[z][i] = acc;
}

// ================= launch =================
extern "C" void kernel_launch(void* const* d_in, const int* in_sizes, int n_in,
                              void* d_out, int out_size, void* d_ws, size_t ws_size,
                              hipStream_t stream) {
  const float* mirna_x = (const float*)d_in[0];
  const float* drug_x  = (const float*)d_in[1];
  const int* edge[4] = { (const int*)d_in[2], (const int*)d_in[4], (const int*)d_in[6], (const int*)d_in[8] };
  const float* attr[4] = { (const float*)d_in[3], (const float*)d_in[5], (const float*)d_in[7], (const float*)d_in[9] };
  const int m[4] = { in_sizes[2] / 2, in_sizes[4] / 2, in_sizes[6] / 2, in_sizes[8] / 2 };
  const int nn4[4] = { NM, NM, ND, ND };
  float* out = (float*)d_out;

  float* ws = (float*)d_ws;
  size_t off = 0;
  auto take = [&](size_t nelem) {
    float* r = ws + off;
    off += (nelem + 255) & ~(size_t)255;
    return r;
  };
  const size_t HN = (size_t)NM * 512, HD = (size_t)ND * 512;
  const size_t HALL = 2 * HN + 2 * HD;
  float* emb_m = take((size_t)NM * 2048);
  float* emb_d = take((size_t)ND * 2048);
  float* region = take(2 * HALL);
  float* h4[4] = { region, region + HN, region + 2 * HN, region + 2 * HN + HD };
  float* xv_m = region;
  float* xv_d = region + (size_t)NM * 2048;
  float* dis_all = take(4 * 2560);
  float* dis4[4] = { dis_all, dis_all + 2560, dis_all + 2 * 2560, dis_all + 3 * 2560 };
  int* cnt_all = (int*)take(4 * 2560);
  int* cnt4[4] = { cnt_all, cnt_all + 2560, cnt_all + 2 * 2560, cnt_all + 3 * 2560 };
  int* rp_all = (int*)take(4 * 2304);
  int* rp4[4] = { rp_all, rp_all + 2304, rp_all + 2 * 2304, rp_all + 3 * 2304 };
  int* col4[4];
  float* val4[4];
  for (int z = 0; z < 4; z++) {
    col4[z] = (int*)take(m[z]);
    val4[z] = take(m[z]);
  }
  unsigned short* Qm = (unsigned short*)take((size_t)NM * 1024);
  unsigned short* Km = (unsigned short*)take((size_t)NM * 1024);
  unsigned short* Vm = (unsigned short*)take((size_t)NM * 1024);
  unsigned short* Qd = (unsigned short*)take((size_t)ND * 1024);
  unsigned short* Kd = (unsigned short*)take((size_t)ND * 1024);
  unsigned short* Vd = (unsigned short*)take((size_t)ND * 1024);
  float* mha_m = take((size_t)NM * 2048);
  float* mha_d = take((size_t)ND * 2048);
  float* y_m = take(HN);
  float* y_d = take(HD);
  unsigned short* yT_m = (unsigned short*)take((size_t)NM * 256);  // NM*512 bf16
  unsigned short* yT_d = (unsigned short*)take((size_t)ND * 256);
  unsigned short* wt = (unsigned short*)take((size_t)16 * 131072);

  int pref = 0;
  int epref[5];
  for (int z = 0; z < 4; z++) { epref[z] = pref; pref += m[z]; }
  epref[4] = pref;

  // -------- weight prep: 0-3 W1, 4-7 W2, 8-11 mir QKVO, 12-15 drug --------
  PrepW pw;
  for (int z = 0; z < 4; z++) {
    pw.W[z] = (const float*)d_in[10 + 4 * z];
    pw.W[4 + z] = (const float*)d_in[12 + 4 * z];
    pw.W[8 + z] = (const float*)d_in[26 + z];
    pw.W[12 + z] = (const float*)d_in[32 + z];
  }
  for (int z = 0; z < 16; z++) pw.Wt[z] = wt + (size_t)z * 262144;
  prep_w<<<dim3(8, 8, 16), 256, 0, stream>>>(pw);

  // -------- CSR build --------
  hipMemsetAsync(dis_all, 0, 4 * 2560 * sizeof(float), stream);
  hipMemsetAsync(cnt_all, 0, 4 * 2560 * sizeof(int), stream);

  DegB db;
  for (int z = 0; z < 4; z++) {
    db.dst[z] = edge[z] + m[z]; db.attr[z] = attr[z];
    db.dis[z] = dis4[z]; db.cnt[z] = cnt4[z];
  }
  for (int z = 0; z < 5; z++) db.epref[z] = epref[z];
  deg_count_b<<<ceil_div(pref, 256), 256, 0, stream>>>(db);

  FinB fn;
  for (int z = 0; z < 4; z++) { fn.dis[z] = dis4[z]; fn.n[z] = nn4[z]; }
  finish_dis_b<<<dim3(ceil_div(ND, 256), 1, 4), 256, 0, stream>>>(fn);

  ScanB sb;
  for (int z = 0; z < 4; z++) { sb.cnt[z] = cnt4[z]; sb.rowptr[z] = rp4[z]; sb.n[z] = nn4[z]; }
  scan_b<<<4, 256, 0, stream>>>(sb);

  hipMemsetAsync(cnt_all, 0, 4 * 2560 * sizeof(int), stream);
  FillB fl;
  for (int z = 0; z < 4; z++) {
    fl.src[z] = edge[z]; fl.dst[z] = edge[z] + m[z]; fl.attr[z] = attr[z];
    fl.rowptr[z] = rp4[z]; fl.cur[z] = cnt4[z]; fl.col[z] = col4[z]; fl.val[z] = val4[z];
  }
  for (int z = 0; z < 5; z++) fl.epref[z] = epref[z];
  fill_b<<<ceil_div(pref, 256), 256, 0, stream>>>(fl);

  // -------- conv1 --------
  BGemm c1;
  const float* xin[4] = { mirna_x, mirna_x, drug_x, drug_x };
  for (int z = 0; z < 6; z++) c1.cs[z] = 1.0f;
  for (int z = 0; z < 4; z++) {
    c1.A[z] = xin[z]; c1.Bt[z] = wt + (size_t)z * 262144; c1.C[z] = h4[z];
    c1.M[z] = nn4[z]; c1.lda[z] = 512;
  }
  for (int z = 4; z < 6; z++) { c1.A[z] = nullptr; c1.Bt[z] = nullptr; c1.C[z] = nullptr; c1.M[z] = 0; c1.lda[z] = 512; }
  gemm_mfma<0, 0><<<dim3(4, ceil_div(ND, 128), 4), 256, 0, stream>>>(c1);

  float* embp[4] = { emb_m, emb_m + 1024, emb_d, emb_d + 1024 };
  GathB g1;
  for (int z = 0; z < 4; z++) {
    g1.rowptr[z] = rp4[z]; g1.col[z] = col4[z]; g1.val[z] = val4[z];
    g1.dis[z] = dis4[z]; g1.h[z] = h4[z]; g1.b[z] = (const float*)d_in[11 + 4 * z];
    g1.out[z] = embp[z]; g1.n[z] = nn4[z];
  }
  gcn_gather_b<<<dim3(ND, 1, 4), 256, 0, stream>>>(g1);

  // -------- conv2 --------
  BGemm c2 = c1;
  for (int z = 0; z < 4; z++) {
    c2.A[z] = embp[z]; c2.Bt[z] = wt + (size_t)(4 + z) * 262144; c2.C[z] = h4[z];
    c2.M[z] = nn4[z]; c2.lda[z] = 2048;
  }
  gemm_mfma<0, 0><<<dim3(4, ceil_div(ND, 128), 4), 256, 0, stream>>>(c2);

  GathB g2 = g1;
  for (int z = 0; z < 4; z++) { g2.b[z] = (const float*)d_in[13 + 4 * z]; g2.out[z] = embp[z] + 512; }
  gcn_gather_b<<<dim3(ND, 1, 4), 256, 0, stream>>>(g2);

  // -------- gather to view layout --------
  GatherB gt;
  gt.emb[0] = emb_m; gt.emb[1] = emb_d; gt.xv[0] = xv_m; gt.xv[1] = xv_d;
  gt.n[0] = NM; gt.n[1] = ND;
  gather_b<<<dim3(ceil_div(ND * 2048, 256), 1, 2), 256, 0, stream>>>(gt);

  // -------- QKV projections (bf16 out; Q pre-scaled by ATT_SC) --------
  BGemm qkv;
  unsigned short* qkvc[6] = { Qm, Km, Vm, Qd, Kd, Vd };
  for (int z = 0; z < 6; z++) {
    qkv.A[z] = (z < 3) ? xv_m : xv_d;
    qkv.Bt[z] = wt + (size_t)((z < 3) ? (8 + z) : (12 + z - 3)) * 262144;
    qkv.C[z] = qkvc[z];
    qkv.M[z] = (z < 3) ? 4 * NM : 4 * ND; qkv.lda[z] = 512;
    qkv.cs[z] = (z == 0 || z == 3) ? ATT_SC : 1.0f;
  }
  gemm_mfma<0, 1><<<dim3(4, ceil_div(4 * ND, 128), 6), 256, 0, stream>>>(qkv);

  // -------- attention (dbuf, bf16 in/out, O -> xv buffers as bf16) --------
  AttArgs aa;
  aa.Q[0] = Qm; aa.K[0] = Km; aa.V[0] = Vm; aa.O[0] = (unsigned short*)xv_m; aa.N[0] = NM;
  aa.Q[1] = Qd; aa.K[1] = Kd; aa.V[1] = Vd; aa.O[1] = (unsigned short*)xv_d; aa.N[1] = ND;
  attn7_kernel<<<dim3(ceil_div(ND, 128), 32, 2), 256, 0, stream>>>(aa);

  // -------- Wo (bf16 A in) --------
  BGemm wo;
  for (int z = 0; z < 6; z++) wo.cs[z] = 1.0f;
  for (int z = 0; z < 2; z++) {
    wo.A[z] = (z == 0) ? xv_m : xv_d;
    wo.Bt[z] = wt + (size_t)(z == 0 ? 11 : 15) * 262144;
    wo.C[z] = (z == 0) ? mha_m : mha_d;
    wo.M[z] = (z == 0) ? 4 * NM : 4 * ND; wo.lda[z] = 512;
  }
  for (int z = 2; z < 6; z++) { wo.A[z] = nullptr; wo.Bt[z] = nullptr; wo.C[z] = nullptr; wo.M[z] = 0; wo.lda[z] = 512; }
  gemm_mfma<1, 0><<<dim3(4, ceil_div(4 * ND, 128), 2), 256, 0, stream>>>(wo);

  // -------- fuse --------
  FuseB fz;
  fz.mha[0] = mha_m; fz.mha[1] = mha_d;
  fz.fw[0] = (const float*)d_in[30]; fz.fw[1] = (const float*)d_in[36];
  fz.fb[0] = (const float*)d_in[31]; fz.fb[1] = (const float*)d_in[37];
  fz.y[0] = y_m; fz.y[1] = y_d;
  fz.n[0] = NM; fz.n[1] = ND;
  fuse_b<<<dim3(ceil_div(ND * 512, 256), 1, 2), 256, 0, stream>>>(fz);

  // -------- y transpose to [i][k] bf16 --------
  PrepYT pyt;
  pyt.y[0] = y_m; pyt.y[1] = y_d;
  pyt.yT[0] = yT_m; pyt.yT[1] = yT_d;
  pyt.n[0] = NM; pyt.n[1] = ND;
  prep_yt<<<dim3(ceil_div(ND, 64), 8, 2), 256, 0, stream>>>(pyt);

  // -------- final TN GEMM (MFMA bf16) --------
  gemm_tn2<<<dim3(ceil_div(ND, 128), ceil_div(NM, 128)), 256, 0, stream>>>(
      yT_m, yT_d, out, NM, ND);
}